// Round 7
// baseline (357.032 us; speedup 1.0000x reference)
//
#include <hip/hip_runtime.h>

typedef __attribute__((ext_vector_type(8))) short short8;
typedef __attribute__((ext_vector_type(4))) float float4f;

#define PITCH 136   // shorts/row in LDS planes
#define ROWS 64     // rows per fwd block (4 row-groups x 16)
#define LOG_SLOPE -2.302585092994046f   // log(0.1)
#define LN2 0.6931471805599453f
#define NBLK 76     // 12 LU + 64 fwd
#define LDS_BYTES 139520   // 8 planes * 64*136*2 + 64 cnt ints
// ws layout (floats): [0] ticket | [2..13] logdet partials | [64..4159] counts
// [4160..5695] fp32 biases | [8192..] W hi/lo ushort planes
#define WS_BIAS 4160
#define WS_WPLANES 8192
#define NWELEM 196608   // 12 * 16384

__device__ __forceinline__ float bf2f(unsigned int u) {
    return __builtin_bit_cast(float, u << 16);
}
__device__ __forceinline__ unsigned short f2bf(float f) {
    unsigned int x = __builtin_bit_cast(unsigned int, f);
    x += 0x7fff + ((x >> 16) & 1);   // round-to-nearest-even
    return (unsigned short)(x >> 16);
}
__device__ __forceinline__ float4f vmsub(float4f a, float s, float4f b) {
    a[0] -= s * b[0]; a[1] -= s * b[1]; a[2] -= s * b[2]; a[3] -= s * b[3];
    return a;
}
__device__ __forceinline__ float4f vscale(float4f a, float s) {
    a[0] *= s; a[1] *= s; a[2] *= s; a[3] *= s;
    return a;
}

template<int ISF32>
__device__ __forceinline__ float ldv(const void* p, int i) {
    if (ISF32) return ((const float*)p)[i];
    return bf2f(((const unsigned short*)p)[i]);
}

// Per-wave dtype sniff: fp32 weights read as u16 pairs have uniform-random
// mantissa halves; bf16 weights have exponent fields in a narrow band.
__device__ __forceinline__ int detect_f32(const unsigned short* W1u, int lane) {
    unsigned int u = W1u[lane * 2];
    unsigned int e = (u >> 7) & 0xFF;
    int bad = (e < 64) || (e > 135);
    return __ballot(bad) != 0ull;
}

__device__ __forceinline__ float4f mfma16(short8 a, short8 b, float4f c) {
    return __builtin_amdgcn_mfma_f32_16x16x32_bf16(a, b, c, 0, 0, 0);
}

__device__ __forceinline__ void split8(float4f a, float4f b, short8& hi, short8& lo) {
#pragma unroll
    for (int j = 0; j < 4; ++j) {
        float v = a[j]; unsigned short h = f2bf(v);
        hi[j] = (short)h; lo[j] = (short)f2bf(v - bf2f(h));
        v = b[j]; h = f2bf(v);
        hi[4 + j] = (short)h; lo[4 + j] = (short)f2bf(v - bf2f(h));
    }
}

// ---- prep: W -> bf16 hi/lo planes, biases -> fp32, zero ticket ----
__global__ void k_prep(const void* __restrict__ W1, const void* __restrict__ W2,
                       const void* __restrict__ W3, const void* __restrict__ b1,
                       const void* __restrict__ b2, const void* __restrict__ b3,
                       float* __restrict__ ws) {
    const int tid = threadIdx.x, bid = blockIdx.x;
    const int isf32 = detect_f32((const unsigned short*)W1, tid & 63);
    unsigned short* whi = (unsigned short*)(ws + WS_WPLANES);
    unsigned short* wlo = whi + NWELEM;
    if (bid < 96) {
        int s = (bid * 256 + tid) * 8;        // 96*256*8 = 196608
        int mat = s >> 14, off = s & 16383;   // mat = wsel*4 + layer
        int wsel = mat >> 2;
        const void* Wm = wsel == 0 ? W1 : (wsel == 1 ? W2 : W3);
        int src = (mat & 3) * 16384 + off;
        short8 hi, lo;
        if (isf32) {
            const float* p = (const float*)Wm + src;
            split8(*(const float4f*)p, *(const float4f*)(p + 4), hi, lo);
        } else {
            hi = *(const short8*)((const unsigned short*)Wm + src);
            lo = (short8){0, 0, 0, 0, 0, 0, 0, 0};
        }
        *(short8*)(whi + s) = hi;
        *(short8*)(wlo + s) = lo;
    } else {
        for (int e = tid; e < 1536; e += 256) {
            int bsel = e >> 9, idx = e & 511;
            const void* bp = bsel == 0 ? b1 : (bsel == 1 ? b2 : b3);
            ws[WS_BIAS + e] = isf32 ? ((const float*)bp)[idx]
                                    : bf2f(((const unsigned short*)bp)[idx]);
        }
        if (tid == 0) ((int*)ws)[0] = 0;   // finalize ticket
    }
}

// Weight fragment set for one matvec: [kk]{w0h,w1h,w0l,w1l}. All static indices.
struct W8 { short8 v[16]; };

__device__ __forceinline__ W8 loadW(const unsigned short* __restrict__ wh,
                                    const unsigned short* __restrict__ wl,
                                    int c0, int c1, int q) {
    W8 r;
#pragma unroll
    for (int kk = 0; kk < 4; ++kk) {
        const int kc = kk * 32 + q * 8;
        r.v[kk * 4 + 0] = *(const short8*)(wh + c0 * 128 + kc);
        r.v[kk * 4 + 1] = *(const short8*)(wh + c1 * 128 + kc);
        r.v[kk * 4 + 2] = *(const short8*)(wl + c0 * 128 + kc);
        r.v[kk * 4 + 3] = *(const short8*)(wl + c1 * 128 + kc);
    }
    return r;
}

// out[ROWS x 128] = act( in[ROWS x 128] @ W^T + bias ); ping-pong planes,
// one barrier per matvec. 16 waves: 4 row-groups (rb) x 4 col-groups (colb);
// each wave owns a 16-row x 32-col output tile => 4 waves/SIMD so ds_read /
// MFMA / L2 latencies of one wave hide behind the other three (r6 diagnosis:
// 1 wave/SIMD left the interval ~90% stalled). Weights for THIS matvec are
// preloaded in `w`; the NEXT matvec's weights prefetch right after the
// barrier so their L2 latency hides behind the MFMAs + epilogue.
// MODE 0: out = leaky(v) | 1: out = res + v | 2: out = leaky(v)+count | 3: count only
template<int MODE>
__device__ __forceinline__ W8 matvec(const W8& w,
        const unsigned short* inh, const unsigned short* inl,
        unsigned short* outh, unsigned short* outl,
        const unsigned short* resh, const unsigned short* resl,
        const unsigned short* __restrict__ nwh, const unsigned short* __restrict__ nwl,
        const float* __restrict__ bias,
        int lane, int colb, int rb, int* cnt) {
    const int m = lane & 15, q = lane >> 4;
    const int c0 = colb + m, c1 = colb + 16 + m;
    float b0 = bias[c0], b1v = bias[c1];
    float4f acc0 = (float4f){b0, b0, b0, b0};
    float4f acc1 = (float4f){b1v, b1v, b1v, b1v};
    __syncthreads();   // previous matvec's LDS writes visible; w's loads drained
    W8 wn = loadW(nwh, nwl, c0, c1, q);   // prefetch next matvec's weights
#pragma unroll
    for (int kk = 0; kk < 4; ++kk) {
        const int kc = kk * 32 + q * 8;
        short8 xh = *(const short8*)(inh + (rb + m) * PITCH + kc);
        short8 xl = *(const short8*)(inl + (rb + m) * PITCH + kc);
        acc0 = mfma16(xh, w.v[kk * 4 + 0], acc0);
        acc0 = mfma16(xl, w.v[kk * 4 + 0], acc0);
        acc0 = mfma16(xh, w.v[kk * 4 + 2], acc0);
        acc1 = mfma16(xh, w.v[kk * 4 + 1], acc1);
        acc1 = mfma16(xl, w.v[kk * 4 + 1], acc1);
        acc1 = mfma16(xh, w.v[kk * 4 + 3], acc1);
    }
    int c[4];
#pragma unroll
    for (int r = 0; r < 4; ++r) {
        float v0 = acc0[r], v1 = acc1[r];
        int row = rb + q * 4 + r;
        int o0 = row * PITCH + c0, o1 = row * PITCH + c1;
        if (MODE == 1) {
            v0 += bf2f(resh[o0]) + bf2f(resl[o0]);
            v1 += bf2f(resh[o1]) + bf2f(resl[o1]);
        }
        if (MODE >= 2) c[r] = (v0 <= 0.0f) + (v1 <= 0.0f);
        if (MODE == 0 || MODE == 2) {
            v0 = v0 > 0.0f ? v0 : 0.1f * v0;
            v1 = v1 > 0.0f ? v1 : 0.1f * v1;
        }
        if (MODE != 3) {
            unsigned short h0 = f2bf(v0);
            outh[o0] = h0; outl[o0] = f2bf(v0 - bf2f(h0));
            unsigned short h1 = f2bf(v1);
            outh[o1] = h1; outl[o1] = f2bf(v1 - bf2f(h1));
        }
    }
    if (MODE >= 2) {
#pragma unroll
        for (int r = 0; r < 4; ++r) {
            int cc = c[r];
            cc += __shfl_xor(cc, 1);
            cc += __shfl_xor(cc, 2);
            cc += __shfl_xor(cc, 4);
            cc += __shfl_xor(cc, 8);
            if (m == 0) atomicAdd(&cnt[rb + q * 4 + r], cc);
        }
    }
    return wn;
}

template<int ISF32>
__device__ __forceinline__ void fwd(int bid, int tid, int lane, char* ldsb,
                                    const void* x, const float* ws, void* out,
                                    float* wsw) {
    unsigned short* P = (unsigned short*)ldsb;
    unsigned short* Ah = P;
    unsigned short* Al = P + 1 * ROWS * PITCH;
    unsigned short* Bh = P + 2 * ROWS * PITCH;
    unsigned short* Bl = P + 3 * ROWS * PITCH;
    unsigned short* Th = P + 4 * ROWS * PITCH;
    unsigned short* Tl = P + 5 * ROWS * PITCH;
    unsigned short* Uh = P + 6 * ROWS * PITCH;
    unsigned short* Ul = P + 7 * ROWS * PITCH;
    int* cnt = (int*)(P + 8 * ROWS * PITCH);
    const unsigned short* whi = (const unsigned short*)(ws + WS_WPLANES);
    const unsigned short* wlo = whi + NWELEM;
    const float* bias = ws + WS_BIAS;
    const int r0 = bid * ROWS;
    const int m = lane & 15, q = lane >> 4;
    const int wv = tid >> 6;               // wave 0..15
    const int colb = (wv & 3) * 32;        // column group
    const int rb = (wv >> 2) * 16;         // row group base
    const int c0 = colb + m, c1 = colb + 16 + m;
    // prefetch layer-0 w1 while staging x into LDS
    W8 wcur = loadW(whi, wlo, c0, c1, q);
    for (int e = tid; e < ROWS * 128; e += 1024) {
        int r = e >> 7, c = e & 127;
        float v = ldv<ISF32>(x, (r0 + r) * 128 + c);
        unsigned short h = f2bf(v);
        Ah[r * PITCH + c] = h;
        Al[r * PITCH + c] = f2bf(v - bf2f(h));
    }
    if (tid < ROWS) cnt[tid] = 0;
    unsigned short *curh = Ah, *curl = Al, *othh = Bh, *othl = Bl;
#pragma unroll 1
    for (int layer = 0; layer < 4; ++layer) {
        const unsigned short* w1h = whi + (0 + layer) * 16384;
        const unsigned short* w1l = wlo + (0 + layer) * 16384;
        const unsigned short* w2h = whi + (4 + layer) * 16384;
        const unsigned short* w2l = wlo + (4 + layer) * 16384;
        const unsigned short* w3h = whi + (8 + layer) * 16384;
        const unsigned short* w3l = wlo + (8 + layer) * 16384;
        const unsigned short* n1h = whi + ((layer + 1) & 3) * 16384;  // next-layer w1
        const unsigned short* n1l = wlo + ((layer + 1) & 3) * 16384;
        const float* b1p = bias + layer * 128;
        const float* b2p = bias + 512 + layer * 128;
        const float* b3p = bias + 1024 + layer * 128;
        wcur = matvec<0>(wcur, curh, curl, Th, Tl, 0, 0, w2h, w2l, b1p, lane, colb, rb, cnt);
        wcur = matvec<0>(wcur, Th, Tl, Uh, Ul, 0, 0, w3h, w3l, b2p, lane, colb, rb, cnt);
        wcur = matvec<1>(wcur, Uh, Ul, othh, othl, curh, curl, w1h, w1l, b3p, lane, colb, rb, cnt);
        wcur = matvec<2>(wcur, othh, othl, Th, Tl, 0, 0, w2h, w2l, b1p, lane, colb, rb, cnt);
        wcur = matvec<3>(wcur, Th, Tl, Th, Tl, 0, 0, n1h, n1l, b2p, lane, colb, rb, cnt);
        unsigned short* t;
        t = curh; curh = othh; othh = t;
        t = curl; curl = othl; othl = t;
    }
    __syncthreads();
    for (int e = tid; e < ROWS * 128; e += 1024) {
        int r = e >> 7, c = e & 127;
        float v = bf2f(curh[r * PITCH + c]) + bf2f(curl[r * PITCH + c]);
        if (ISF32) ((float*)out)[(r0 + r) * 128 + c] = v;
        else ((unsigned short*)out)[(r0 + r) * 128 + c] = f2bf(v);
    }
    if (tid < ROWS) wsw[64 + r0 + tid] = (float)cnt[tid];
}

// ---- register-resident unpivoted LU, RANK-4 per barrier (32 intervals).
// Runs on waves 0..3 of LU blocks (tid 0..255); waves 4..15 exit at kernel
// top, so the internal __syncthreads covers only live waves.
template<int ISF32>
__device__ __forceinline__ float lu_logdet(int id, int tid, float* lds,
        const void* W1, const void* W2, const void* W3) {
    const int wsel = id % 3;
    const void* Wm = (wsel == 0 ? W1 : (wsel == 1 ? W2 : W3));
    const int ofs = (id / 3) * 16384;
    const int tx = tid & 31, ty = tid >> 5;
    float* rowbuf = lds;          // [2][4][128]: rows K..K+3
    float* colbuf = lds + 1024;   // [2][4][128]: cols K..K+3 packed [j][ty*16+m]
    float4f V[16];                // A[ty+8m][4tx..4tx+3]
#pragma unroll
    for (int m = 0; m < 16; ++m) {
        int base = ofs + (ty + 8 * m) * 128 + 4 * tx;
        if (ISF32) {
            V[m] = *(const float4f*)((const float*)Wm + base);
        } else {
            ushort4 u = *(const ushort4*)((const unsigned short*)Wm + base);
            V[m] = (float4f){bf2f(u.x), bf2f(u.y), bf2f(u.z), bf2f(u.w)};
        }
    }
    // stage interval 0: rows 0..3 (ty 0..3, all m=0), cols 0..3 (owner tx==0)
    if (ty < 4) *(float4f*)&rowbuf[ty * 128 + 4 * tx] = V[0];
    if (tx == 0) {
#pragma unroll
        for (int j = 0; j < 4; ++j) {
#pragma unroll
            for (int mg = 0; mg < 4; ++mg) {
                float4f t = {V[mg * 4 + 0][j], V[mg * 4 + 1][j],
                             V[mg * 4 + 2][j], V[mg * 4 + 3][j]};
                *(float4f*)&colbuf[j * 128 + ty * 16 + mg * 4] = t;
            }
        }
    }
    __syncthreads();
    float logacc = 0.0f;
#pragma unroll 1
    for (int kap = 0; kap < 32; ++kap) {
        const int K = kap * 4;
        const int buf = (kap & 1) * 512;
        float4f D[4], R[4], C[4][4];
#pragma unroll
        for (int j = 0; j < 4; ++j) {
            D[j] = *(const float4f*)&rowbuf[buf + j * 128 + K];       // broadcast
            R[j] = *(const float4f*)&rowbuf[buf + j * 128 + 4 * tx];
#pragma unroll
            for (int mg = 0; mg < 4; ++mg)
                C[j][mg] = *(const float4f*)&colbuf[buf + j * 128 + ty * 16 + mg * 4];
        }
        // 4x4 panel factorization, redundant per thread
        float p0 = D[0][0], i0 = 1.0f / p0;
        float l10 = D[1][0] * i0, l20 = D[2][0] * i0, l30 = D[3][0] * i0;
        D[1] = vmsub(D[1], l10, D[0]); R[1] = vmsub(R[1], l10, R[0]);
        D[2] = vmsub(D[2], l20, D[0]); R[2] = vmsub(R[2], l20, R[0]);
        D[3] = vmsub(D[3], l30, D[0]); R[3] = vmsub(R[3], l30, R[0]);
        float p1 = D[1][1], i1 = 1.0f / p1;
        float l21 = D[2][1] * i1, l31 = D[3][1] * i1;
        D[2] = vmsub(D[2], l21, D[1]); R[2] = vmsub(R[2], l21, R[1]);
        D[3] = vmsub(D[3], l31, D[1]); R[3] = vmsub(R[3], l31, R[1]);
        float p2 = D[2][2], i2 = 1.0f / p2;
        float l32 = D[3][2] * i2;
        D[3] = vmsub(D[3], l32, D[2]); R[3] = vmsub(R[3], l32, R[2]);
        float p3 = D[3][3], i3 = 1.0f / p3;
        logacc += __log2f(fabsf(p0)) + __log2f(fabsf(p1))
                + __log2f(fabsf(p2)) + __log2f(fabsf(p3));
        // back-substitution: X = Upanel^{-1} * R  (solve U X = R, U upper-tri)
        float4f X3 = vscale(R[3], i3);
        float4f X2 = vscale(vmsub(R[2], D[2][3], X3), i2);
        float4f X1 = vscale(vmsub(vmsub(R[1], D[1][2], X2), D[1][3], X3), i1);
        float4f X0 = vscale(vmsub(vmsub(vmsub(R[0], D[0][1], X1),
                                        D[0][2], X2), D[0][3], X3), i0);
        // rank-4 trailing update with RAW column values (no masking needed)
#pragma unroll
        for (int mg = 0; mg < 4; ++mg) {
#pragma unroll
            for (int e = 0; e < 4; ++e) {
                float4f v = V[mg * 4 + e];
                v = vmsub(v, C[0][mg][e], X0);
                v = vmsub(v, C[1][mg][e], X1);
                v = vmsub(v, C[2][mg][e], X2);
                v = vmsub(v, C[3][mg][e], X3);
                V[mg * 4 + e] = v;
            }
        }
        // stage next interval (rows/cols K+4..K+7)
        if (kap < 31) {
            const int nbuf = ((kap + 1) & 1) * 512;
            const int tb = (kap & 1) ? 0 : 4;     // rows K+4..K+7 -> ty in [tb,tb+4)
            const int mn = (kap + 1) >> 1;        // their m index (uniform)
            if (ty >= tb && ty < tb + 4) {
                float4f val;
                switch (mn) {                     // uniform switch, static reg index
                case 0:  val = V[0];  break; case 1:  val = V[1];  break;
                case 2:  val = V[2];  break; case 3:  val = V[3];  break;
                case 4:  val = V[4];  break; case 5:  val = V[5];  break;
                case 6:  val = V[6];  break; case 7:  val = V[7];  break;
                case 8:  val = V[8];  break; case 9:  val = V[9];  break;
                case 10: val = V[10]; break; case 11: val = V[11]; break;
                case 12: val = V[12]; break; case 13: val = V[13]; break;
                case 14: val = V[14]; break; default: val = V[15]; break;
                }
                *(float4f*)&rowbuf[nbuf + (ty - tb) * 128 + 4 * tx] = val;
            }
            if (tx == kap + 1) {   // owner of cols K+4..K+7 (4-aligned)
#pragma unroll
                for (int j = 0; j < 4; ++j) {
#pragma unroll
                    for (int mg = 0; mg < 4; ++mg) {
                        float4f t = {V[mg * 4 + 0][j], V[mg * 4 + 1][j],
                                     V[mg * 4 + 2][j], V[mg * 4 + 3][j]};
                        *(float4f*)&colbuf[nbuf + j * 128 + ty * 16 + mg * 4] = t;
                    }
                }
            }
        }
        __syncthreads();   // one barrier per 4 pivots
    }
    return logacc * LN2;
}

__global__ __launch_bounds__(1024) void k_main(
        const void* __restrict__ x,
        const void* __restrict__ W1, const void* __restrict__ b1,
        const void* __restrict__ W2, const void* __restrict__ b2,
        const void* __restrict__ W3, const void* __restrict__ b3,
        void* __restrict__ out, float* __restrict__ ws) {
    extern __shared__ __align__(16) char ldsb[];
    __shared__ int s_last;
    const int tid = threadIdx.x;
    const int lane = tid & 63;
    // LU blocks use 256 threads; waves 4..15 exit before any barrier
    if (blockIdx.x < 12 && tid >= 256) return;
    const int isf32 = detect_f32((const unsigned short*)W1, lane);

    if (blockIdx.x < 12) {
        float ld = isf32 ? lu_logdet<1>(blockIdx.x, tid, (float*)ldsb, W1, W2, W3)
                         : lu_logdet<0>(blockIdx.x, tid, (float*)ldsb, W1, W2, W3);
        if (tid == 0) ws[2 + blockIdx.x] = ld;
    } else {
        const int bid = blockIdx.x - 12;
        if (isf32) fwd<1>(bid, tid, lane, ldsb, x, ws, out, ws);
        else       fwd<0>(bid, tid, lane, ldsb, x, ws, out, ws);
    }

    // ---- last-block finalize (works with 256 or 1024 live threads) ----
    __threadfence();
    if (tid == 0) s_last = (atomicAdd((int*)ws, 1) == NBLK - 1);
    __syncthreads();
    if (!s_last) return;
    __threadfence();   // acquire: other blocks' ws writes now visible
    if (tid < 256) {
        float s = 0.0f;
#pragma unroll
        for (int i = 0; i < 12; ++i) s += ws[2 + i];
        for (int b = tid; b < 4096; b += 256) {
            float v = s + LOG_SLOPE * ws[64 + b];
            if (isf32) ((float*)out)[524288 + b] = v;
            else ((unsigned short*)out)[524288 + b] = f2bf(v);
        }
    }
}

extern "C" void kernel_launch(void* const* d_in, const int* in_sizes, int n_in,
                              void* d_out, int out_size, void* d_ws, size_t ws_size,
                              hipStream_t stream) {
    const void* x  = d_in[0];
    const void* W1 = d_in[1];
    const void* b1 = d_in[2];
    const void* W2 = d_in[3];
    const void* b2 = d_in[4];
    const void* W3 = d_in[5];
    const void* b3 = d_in[6];
    float* ws = (float*)d_ws;

    hipLaunchKernelGGL(k_prep, dim3(97), dim3(256), 0, stream,
                       W1, W2, W3, b1, b2, b3, ws);
    hipLaunchKernelGGL(k_main, dim3(NBLK), dim3(1024), LDS_BYTES, stream,
                       x, W1, b1, W2, b2, W3, b3, d_out, ws);
}

// Round 8
// 170.562 us; speedup vs baseline: 2.0933x; 2.0933x over previous
//
#include <hip/hip_runtime.h>

typedef __attribute__((ext_vector_type(8))) short short8;
typedef __attribute__((ext_vector_type(4))) float float4f;

#define PITCH 136   // shorts/row in LDS planes
#define ROWS 32     // rows per fwd block (2 row-groups x 16)
#define LOG_SLOPE -2.302585092994046f   // log(0.1)
#define LN2 0.6931471805599453f
#define NBLK 140    // 12 LU + 128 fwd
#define LDS_BYTES 69760   // 8 planes * 32*136*2 + 128 cnt
// ws layout (floats): [0] ticket | [2..13] logdet partials | [64..4159] counts
// [4160..5695] fp32 biases | [8192..] W hi/lo ushort planes
#define WS_BIAS 4160
#define WS_WPLANES 8192
#define NWELEM 196608   // 12 * 16384

__device__ __forceinline__ float bf2f(unsigned int u) {
    return __builtin_bit_cast(float, u << 16);
}
__device__ __forceinline__ unsigned short f2bf(float f) {
    unsigned int x = __builtin_bit_cast(unsigned int, f);
    x += 0x7fff + ((x >> 16) & 1);   // round-to-nearest-even
    return (unsigned short)(x >> 16);
}
__device__ __forceinline__ float4f vmsub(float4f a, float s, float4f b) {
    a[0] -= s * b[0]; a[1] -= s * b[1]; a[2] -= s * b[2]; a[3] -= s * b[3];
    return a;
}
__device__ __forceinline__ float4f vscale(float4f a, float s) {
    a[0] *= s; a[1] *= s; a[2] *= s; a[3] *= s;
    return a;
}

template<int ISF32>
__device__ __forceinline__ float ldv(const void* p, int i) {
    if (ISF32) return ((const float*)p)[i];
    return bf2f(((const unsigned short*)p)[i]);
}

// Per-wave dtype sniff: fp32 weights read as u16 pairs have uniform-random
// mantissa halves; bf16 weights have exponent fields in a narrow band.
__device__ __forceinline__ int detect_f32(const unsigned short* W1u, int lane) {
    unsigned int u = W1u[lane * 2];
    unsigned int e = (u >> 7) & 0xFF;
    int bad = (e < 64) || (e > 135);
    return __ballot(bad) != 0ull;
}

__device__ __forceinline__ float4f mfma16(short8 a, short8 b, float4f c) {
    return __builtin_amdgcn_mfma_f32_16x16x32_bf16(a, b, c, 0, 0, 0);
}

__device__ __forceinline__ void split8(float4f a, float4f b, short8& hi, short8& lo) {
#pragma unroll
    for (int j = 0; j < 4; ++j) {
        float v = a[j]; unsigned short h = f2bf(v);
        hi[j] = (short)h; lo[j] = (short)f2bf(v - bf2f(h));
        v = b[j]; h = f2bf(v);
        hi[4 + j] = (short)h; lo[4 + j] = (short)f2bf(v - bf2f(h));
    }
}

// ---- prep: W -> bf16 hi/lo planes, biases -> fp32, zero ticket ----
__global__ void k_prep(const void* __restrict__ W1, const void* __restrict__ W2,
                       const void* __restrict__ W3, const void* __restrict__ b1,
                       const void* __restrict__ b2, const void* __restrict__ b3,
                       float* __restrict__ ws) {
    const int tid = threadIdx.x, bid = blockIdx.x;
    const int isf32 = detect_f32((const unsigned short*)W1, tid & 63);
    unsigned short* whi = (unsigned short*)(ws + WS_WPLANES);
    unsigned short* wlo = whi + NWELEM;
    if (bid < 96) {
        int s = (bid * 256 + tid) * 8;        // 96*256*8 = 196608
        int mat = s >> 14, off = s & 16383;   // mat = wsel*4 + layer
        int wsel = mat >> 2;
        const void* Wm = wsel == 0 ? W1 : (wsel == 1 ? W2 : W3);
        int src = (mat & 3) * 16384 + off;
        short8 hi, lo;
        if (isf32) {
            const float* p = (const float*)Wm + src;
            split8(*(const float4f*)p, *(const float4f*)(p + 4), hi, lo);
        } else {
            hi = *(const short8*)((const unsigned short*)Wm + src);
            lo = (short8){0, 0, 0, 0, 0, 0, 0, 0};
        }
        *(short8*)(whi + s) = hi;
        *(short8*)(wlo + s) = lo;
    } else {
        for (int e = tid; e < 1536; e += 256) {
            int bsel = e >> 9, idx = e & 511;
            const void* bp = bsel == 0 ? b1 : (bsel == 1 ? b2 : b3);
            ws[WS_BIAS + e] = isf32 ? ((const float*)bp)[idx]
                                    : bf2f(((const unsigned short*)bp)[idx]);
        }
        if (tid == 0) ((int*)ws)[0] = 0;   // finalize ticket
    }
}

// Weight fragment set for one matvec: [kk]{w0h,w1h,w0l,w1l}. All static indices.
struct W8 { short8 v[16]; };

__device__ __forceinline__ W8 loadW(const unsigned short* __restrict__ wh,
                                    const unsigned short* __restrict__ wl,
                                    int c0, int c1, int q) {
    W8 r;
#pragma unroll
    for (int kk = 0; kk < 4; ++kk) {
        const int kc = kk * 32 + q * 8;
        r.v[kk * 4 + 0] = *(const short8*)(wh + c0 * 128 + kc);
        r.v[kk * 4 + 1] = *(const short8*)(wh + c1 * 128 + kc);
        r.v[kk * 4 + 2] = *(const short8*)(wl + c0 * 128 + kc);
        r.v[kk * 4 + 3] = *(const short8*)(wl + c1 * 128 + kc);
    }
    return r;
}

// out[ROWS x 128] = act( in[ROWS x 128] @ W^T + bias ); ping-pong planes,
// one barrier per matvec. 8 waves: 2 row-groups (rb) x 4 col-groups (colb);
// each wave owns a 16x32 output tile => 2 waves/SIMD, so one wave's ds_read /
// MFMA-dep / vmcnt stalls hide behind the other (r6: 1 wave/SIMD left the
// interval ~90% stalled). Weights for THIS matvec are preloaded in `w`; the
// NEXT matvec's weights prefetch right after the barrier so their L2 latency
// hides behind the MFMAs + epilogue.
// MODE 0: out = leaky(v) | 1: out = res + v | 2: out = leaky(v)+count | 3: count only
template<int MODE>
__device__ __forceinline__ W8 matvec(const W8& w,
        const unsigned short* inh, const unsigned short* inl,
        unsigned short* outh, unsigned short* outl,
        const unsigned short* resh, const unsigned short* resl,
        const unsigned short* __restrict__ nwh, const unsigned short* __restrict__ nwl,
        const float* __restrict__ bias,
        int lane, int colb, int rb, int* cnt) {
    const int m = lane & 15, q = lane >> 4;
    const int c0 = colb + m, c1 = colb + 16 + m;
    float b0 = bias[c0], b1v = bias[c1];
    float4f acc0 = (float4f){b0, b0, b0, b0};
    float4f acc1 = (float4f){b1v, b1v, b1v, b1v};
    __syncthreads();   // previous matvec's LDS writes visible; w's loads drained
    W8 wn = loadW(nwh, nwl, c0, c1, q);   // prefetch next matvec's weights
#pragma unroll
    for (int kk = 0; kk < 4; ++kk) {
        const int kc = kk * 32 + q * 8;
        short8 xh = *(const short8*)(inh + (rb + m) * PITCH + kc);
        short8 xl = *(const short8*)(inl + (rb + m) * PITCH + kc);
        acc0 = mfma16(xh, w.v[kk * 4 + 0], acc0);
        acc0 = mfma16(xl, w.v[kk * 4 + 0], acc0);
        acc0 = mfma16(xh, w.v[kk * 4 + 2], acc0);
        acc1 = mfma16(xh, w.v[kk * 4 + 1], acc1);
        acc1 = mfma16(xl, w.v[kk * 4 + 1], acc1);
        acc1 = mfma16(xh, w.v[kk * 4 + 3], acc1);
    }
    int c[4];
#pragma unroll
    for (int r = 0; r < 4; ++r) {
        float v0 = acc0[r], v1 = acc1[r];
        int row = rb + q * 4 + r;
        int o0 = row * PITCH + c0, o1 = row * PITCH + c1;
        if (MODE == 1) {
            v0 += bf2f(resh[o0]) + bf2f(resl[o0]);
            v1 += bf2f(resh[o1]) + bf2f(resl[o1]);
        }
        if (MODE >= 2) c[r] = (v0 <= 0.0f) + (v1 <= 0.0f);
        if (MODE == 0 || MODE == 2) {
            v0 = v0 > 0.0f ? v0 : 0.1f * v0;
            v1 = v1 > 0.0f ? v1 : 0.1f * v1;
        }
        if (MODE != 3) {
            unsigned short h0 = f2bf(v0);
            outh[o0] = h0; outl[o0] = f2bf(v0 - bf2f(h0));
            unsigned short h1 = f2bf(v1);
            outh[o1] = h1; outl[o1] = f2bf(v1 - bf2f(h1));
        }
    }
    if (MODE >= 2) {
#pragma unroll
        for (int r = 0; r < 4; ++r) {
            int cc = c[r];
            cc += __shfl_xor(cc, 1);
            cc += __shfl_xor(cc, 2);
            cc += __shfl_xor(cc, 4);
            cc += __shfl_xor(cc, 8);
            if (m == 0) atomicAdd(&cnt[rb + q * 4 + r], cc);
        }
    }
    return wn;
}

template<int ISF32>
__device__ __forceinline__ void fwd(int bid, int tid, int lane, char* ldsb,
                                    const void* x, const float* ws, void* out,
                                    float* wsw) {
    unsigned short* P = (unsigned short*)ldsb;
    unsigned short* Ah = P;
    unsigned short* Al = P + 1 * ROWS * PITCH;
    unsigned short* Bh = P + 2 * ROWS * PITCH;
    unsigned short* Bl = P + 3 * ROWS * PITCH;
    unsigned short* Th = P + 4 * ROWS * PITCH;
    unsigned short* Tl = P + 5 * ROWS * PITCH;
    unsigned short* Uh = P + 6 * ROWS * PITCH;
    unsigned short* Ul = P + 7 * ROWS * PITCH;
    int* cnt = (int*)(P + 8 * ROWS * PITCH);
    const unsigned short* whi = (const unsigned short*)(ws + WS_WPLANES);
    const unsigned short* wlo = whi + NWELEM;
    const float* bias = ws + WS_BIAS;
    const int r0 = bid * ROWS;
    const int m = lane & 15, q = lane >> 4;
    const int wv = tid >> 6;               // wave 0..7
    const int colb = (wv & 3) * 32;        // column group
    const int rb = (wv >> 2) * 16;         // row group base
    const int c0 = colb + m, c1 = colb + 16 + m;
    // prefetch layer-0 w1 while staging x into LDS
    W8 wcur = loadW(whi, wlo, c0, c1, q);
    for (int e = tid; e < ROWS * 128; e += 512) {
        int r = e >> 7, c = e & 127;
        float v = ldv<ISF32>(x, (r0 + r) * 128 + c);
        unsigned short h = f2bf(v);
        Ah[r * PITCH + c] = h;
        Al[r * PITCH + c] = f2bf(v - bf2f(h));
    }
    if (tid < ROWS) cnt[tid] = 0;
    unsigned short *curh = Ah, *curl = Al, *othh = Bh, *othl = Bl;
#pragma unroll 1
    for (int layer = 0; layer < 4; ++layer) {
        const unsigned short* w1h = whi + (0 + layer) * 16384;
        const unsigned short* w1l = wlo + (0 + layer) * 16384;
        const unsigned short* w2h = whi + (4 + layer) * 16384;
        const unsigned short* w2l = wlo + (4 + layer) * 16384;
        const unsigned short* w3h = whi + (8 + layer) * 16384;
        const unsigned short* w3l = wlo + (8 + layer) * 16384;
        const unsigned short* n1h = whi + ((layer + 1) & 3) * 16384;  // next-layer w1
        const unsigned short* n1l = wlo + ((layer + 1) & 3) * 16384;
        const float* b1p = bias + layer * 128;
        const float* b2p = bias + 512 + layer * 128;
        const float* b3p = bias + 1024 + layer * 128;
        wcur = matvec<0>(wcur, curh, curl, Th, Tl, 0, 0, w2h, w2l, b1p, lane, colb, rb, cnt);
        wcur = matvec<0>(wcur, Th, Tl, Uh, Ul, 0, 0, w3h, w3l, b2p, lane, colb, rb, cnt);
        wcur = matvec<1>(wcur, Uh, Ul, othh, othl, curh, curl, w1h, w1l, b3p, lane, colb, rb, cnt);
        wcur = matvec<2>(wcur, othh, othl, Th, Tl, 0, 0, w2h, w2l, b1p, lane, colb, rb, cnt);
        wcur = matvec<3>(wcur, Th, Tl, Th, Tl, 0, 0, n1h, n1l, b2p, lane, colb, rb, cnt);
        unsigned short* t;
        t = curh; curh = othh; othh = t;
        t = curl; curl = othl; othl = t;
    }
    __syncthreads();
    for (int e = tid; e < ROWS * 128; e += 512) {
        int r = e >> 7, c = e & 127;
        float v = bf2f(curh[r * PITCH + c]) + bf2f(curl[r * PITCH + c]);
        if (ISF32) ((float*)out)[(r0 + r) * 128 + c] = v;
        else ((unsigned short*)out)[(r0 + r) * 128 + c] = f2bf(v);
    }
    if (tid < ROWS) wsw[64 + r0 + tid] = (float)cnt[tid];
}

// ---- register-resident unpivoted LU, RANK-4 per barrier (32 intervals).
// Runs on waves 0..3 of LU blocks (tid 0..255); waves 4..7 exit at kernel
// top, so the internal __syncthreads covers only live waves.
template<int ISF32>
__device__ __forceinline__ float lu_logdet(int id, int tid, float* lds,
        const void* W1, const void* W2, const void* W3) {
    const int wsel = id % 3;
    const void* Wm = (wsel == 0 ? W1 : (wsel == 1 ? W2 : W3));
    const int ofs = (id / 3) * 16384;
    const int tx = tid & 31, ty = tid >> 5;
    float* rowbuf = lds;          // [2][4][128]: rows K..K+3
    float* colbuf = lds + 1024;   // [2][4][128]: cols K..K+3 packed [j][ty*16+m]
    float4f V[16];                // A[ty+8m][4tx..4tx+3]
#pragma unroll
    for (int m = 0; m < 16; ++m) {
        int base = ofs + (ty + 8 * m) * 128 + 4 * tx;
        if (ISF32) {
            V[m] = *(const float4f*)((const float*)Wm + base);
        } else {
            ushort4 u = *(const ushort4*)((const unsigned short*)Wm + base);
            V[m] = (float4f){bf2f(u.x), bf2f(u.y), bf2f(u.z), bf2f(u.w)};
        }
    }
    // stage interval 0: rows 0..3 (ty 0..3, all m=0), cols 0..3 (owner tx==0)
    if (ty < 4) *(float4f*)&rowbuf[ty * 128 + 4 * tx] = V[0];
    if (tx == 0) {
#pragma unroll
        for (int j = 0; j < 4; ++j) {
#pragma unroll
            for (int mg = 0; mg < 4; ++mg) {
                float4f t = {V[mg * 4 + 0][j], V[mg * 4 + 1][j],
                             V[mg * 4 + 2][j], V[mg * 4 + 3][j]};
                *(float4f*)&colbuf[j * 128 + ty * 16 + mg * 4] = t;
            }
        }
    }
    __syncthreads();
    float logacc = 0.0f;
#pragma unroll 1
    for (int kap = 0; kap < 32; ++kap) {
        const int K = kap * 4;
        const int buf = (kap & 1) * 512;
        float4f D[4], R[4], C[4][4];
#pragma unroll
        for (int j = 0; j < 4; ++j) {
            D[j] = *(const float4f*)&rowbuf[buf + j * 128 + K];       // broadcast
            R[j] = *(const float4f*)&rowbuf[buf + j * 128 + 4 * tx];
#pragma unroll
            for (int mg = 0; mg < 4; ++mg)
                C[j][mg] = *(const float4f*)&colbuf[buf + j * 128 + ty * 16 + mg * 4];
        }
        // 4x4 panel factorization, redundant per thread
        float p0 = D[0][0], i0 = 1.0f / p0;
        float l10 = D[1][0] * i0, l20 = D[2][0] * i0, l30 = D[3][0] * i0;
        D[1] = vmsub(D[1], l10, D[0]); R[1] = vmsub(R[1], l10, R[0]);
        D[2] = vmsub(D[2], l20, D[0]); R[2] = vmsub(R[2], l20, R[0]);
        D[3] = vmsub(D[3], l30, D[0]); R[3] = vmsub(R[3], l30, R[0]);
        float p1 = D[1][1], i1 = 1.0f / p1;
        float l21 = D[2][1] * i1, l31 = D[3][1] * i1;
        D[2] = vmsub(D[2], l21, D[1]); R[2] = vmsub(R[2], l21, R[1]);
        D[3] = vmsub(D[3], l31, D[1]); R[3] = vmsub(R[3], l31, R[1]);
        float p2 = D[2][2], i2 = 1.0f / p2;
        float l32 = D[3][2] * i2;
        D[3] = vmsub(D[3], l32, D[2]); R[3] = vmsub(R[3], l32, R[2]);
        float p3 = D[3][3], i3 = 1.0f / p3;
        logacc += __log2f(fabsf(p0)) + __log2f(fabsf(p1))
                + __log2f(fabsf(p2)) + __log2f(fabsf(p3));
        // back-substitution: X = Upanel^{-1} * R  (solve U X = R, U upper-tri)
        float4f X3 = vscale(R[3], i3);
        float4f X2 = vscale(vmsub(R[2], D[2][3], X3), i2);
        float4f X1 = vscale(vmsub(vmsub(R[1], D[1][2], X2), D[1][3], X3), i1);
        float4f X0 = vscale(vmsub(vmsub(vmsub(R[0], D[0][1], X1),
                                        D[0][2], X2), D[0][3], X3), i0);
        // rank-4 trailing update with RAW column values (no masking needed)
#pragma unroll
        for (int mg = 0; mg < 4; ++mg) {
#pragma unroll
            for (int e = 0; e < 4; ++e) {
                float4f v = V[mg * 4 + e];
                v = vmsub(v, C[0][mg][e], X0);
                v = vmsub(v, C[1][mg][e], X1);
                v = vmsub(v, C[2][mg][e], X2);
                v = vmsub(v, C[3][mg][e], X3);
                V[mg * 4 + e] = v;
            }
        }
        // stage next interval (rows/cols K+4..K+7)
        if (kap < 31) {
            const int nbuf = ((kap + 1) & 1) * 512;
            const int tb = (kap & 1) ? 0 : 4;     // rows K+4..K+7 -> ty in [tb,tb+4)
            const int mn = (kap + 1) >> 1;        // their m index (uniform)
            if (ty >= tb && ty < tb + 4) {
                float4f val;
                switch (mn) {                     // uniform switch, static reg index
                case 0:  val = V[0];  break; case 1:  val = V[1];  break;
                case 2:  val = V[2];  break; case 3:  val = V[3];  break;
                case 4:  val = V[4];  break; case 5:  val = V[5];  break;
                case 6:  val = V[6];  break; case 7:  val = V[7];  break;
                case 8:  val = V[8];  break; case 9:  val = V[9];  break;
                case 10: val = V[10]; break; case 11: val = V[11]; break;
                case 12: val = V[12]; break; case 13: val = V[13]; break;
                case 14: val = V[14]; break; default: val = V[15]; break;
                }
                *(float4f*)&rowbuf[nbuf + (ty - tb) * 128 + 4 * tx] = val;
            }
            if (tx == kap + 1) {   // owner of cols K+4..K+7 (4-aligned)
#pragma unroll
                for (int j = 0; j < 4; ++j) {
#pragma unroll
                    for (int mg = 0; mg < 4; ++mg) {
                        float4f t = {V[mg * 4 + 0][j], V[mg * 4 + 1][j],
                                     V[mg * 4 + 2][j], V[mg * 4 + 3][j]};
                        *(float4f*)&colbuf[nbuf + j * 128 + ty * 16 + mg * 4] = t;
                    }
                }
            }
        }
        __syncthreads();   // one barrier per 4 pivots
    }
    return logacc * LN2;
}

__global__ __launch_bounds__(512, 2) void k_main(
        const void* __restrict__ x,
        const void* __restrict__ W1, const void* __restrict__ b1,
        const void* __restrict__ W2, const void* __restrict__ b2,
        const void* __restrict__ W3, const void* __restrict__ b3,
        void* __restrict__ out, float* __restrict__ ws) {
    extern __shared__ __align__(16) char ldsb[];
    __shared__ int s_last;
    const int tid = threadIdx.x;
    const int lane = tid & 63;
    // LU blocks use 256 threads; waves 4..7 exit before any barrier
    if (blockIdx.x < 12 && tid >= 256) return;
    const int isf32 = detect_f32((const unsigned short*)W1, lane);

    if (blockIdx.x < 12) {
        float ld = isf32 ? lu_logdet<1>(blockIdx.x, tid, (float*)ldsb, W1, W2, W3)
                         : lu_logdet<0>(blockIdx.x, tid, (float*)ldsb, W1, W2, W3);
        if (tid == 0) ws[2 + blockIdx.x] = ld;
    } else {
        const int bid = blockIdx.x - 12;
        if (isf32) fwd<1>(bid, tid, lane, ldsb, x, ws, out, ws);
        else       fwd<0>(bid, tid, lane, ldsb, x, ws, out, ws);
    }

    // ---- last-block finalize (LU last-finisher has 256 live threads) ----
    __threadfence();
    if (tid == 0) s_last = (atomicAdd((int*)ws, 1) == NBLK - 1);
    __syncthreads();
    if (!s_last) return;
    __threadfence();   // acquire: other blocks' ws writes now visible
    if (tid < 256) {
        float s = 0.0f;
#pragma unroll
        for (int i = 0; i < 12; ++i) s += ws[2 + i];
        for (int b = tid; b < 4096; b += 256) {
            float v = s + LOG_SLOPE * ws[64 + b];
            if (isf32) ((float*)out)[524288 + b] = v;
            else ((unsigned short*)out)[524288 + b] = f2bf(v);
        }
    }
}

extern "C" void kernel_launch(void* const* d_in, const int* in_sizes, int n_in,
                              void* d_out, int out_size, void* d_ws, size_t ws_size,
                              hipStream_t stream) {
    const void* x  = d_in[0];
    const void* W1 = d_in[1];
    const void* b1 = d_in[2];
    const void* W2 = d_in[3];
    const void* b2 = d_in[4];
    const void* W3 = d_in[5];
    const void* b3 = d_in[6];
    float* ws = (float*)d_ws;

    hipLaunchKernelGGL(k_prep, dim3(97), dim3(256), 0, stream,
                       W1, W2, W3, b1, b2, b3, ws);
    hipLaunchKernelGGL(k_main, dim3(NBLK), dim3(512), LDS_BYTES, stream,
                       x, W1, b1, W2, b2, W3, b3, d_out, ws);
}

// Round 9
// 140.277 us; speedup vs baseline: 2.5452x; 1.2159x over previous
//
#include <hip/hip_runtime.h>

typedef __attribute__((ext_vector_type(8))) short short8;
typedef __attribute__((ext_vector_type(4))) float float4f;

#define PITCH 136   // shorts/row in LDS planes
#define ROWS 32     // rows per fwd block
#define LOG_SLOPE -2.302585092994046f   // log(0.1)
#define LN2 0.6931471805599453f
#define NBLK 140    // 12 LU + 128 fwd
#define LDS_BYTES 69760   // 8 planes * 32*136*2 + 128 cnt
// ws layout (floats): [0] ticket | [2..13] logdet partials | [64..4159] counts
// [4160..5695] fp32 biases | [8192..] W hi/lo ushort planes
#define WS_BIAS 4160
#define WS_WPLANES 8192
#define NWELEM 196608   // 12 * 16384

__device__ __forceinline__ float bf2f(unsigned int u) {
    return __builtin_bit_cast(float, u << 16);
}
__device__ __forceinline__ unsigned short f2bf(float f) {
    unsigned int x = __builtin_bit_cast(unsigned int, f);
    x += 0x7fff + ((x >> 16) & 1);   // round-to-nearest-even
    return (unsigned short)(x >> 16);
}
__device__ __forceinline__ float4f vmsub(float4f a, float s, float4f b) {
    a[0] -= s * b[0]; a[1] -= s * b[1]; a[2] -= s * b[2]; a[3] -= s * b[3];
    return a;
}
__device__ __forceinline__ float4f vscale(float4f a, float s) {
    a[0] *= s; a[1] *= s; a[2] *= s; a[3] *= s;
    return a;
}

template<int ISF32>
__device__ __forceinline__ float ldv(const void* p, int i) {
    if (ISF32) return ((const float*)p)[i];
    return bf2f(((const unsigned short*)p)[i]);
}

// Per-wave dtype sniff: fp32 weights read as u16 pairs have uniform-random
// mantissa halves; bf16 weights have exponent fields in a narrow band.
__device__ __forceinline__ int detect_f32(const unsigned short* W1u, int lane) {
    unsigned int u = W1u[lane * 2];
    unsigned int e = (u >> 7) & 0xFF;
    int bad = (e < 64) || (e > 135);
    return __ballot(bad) != 0ull;
}

__device__ __forceinline__ float4f mfma16(short8 a, short8 b, float4f c) {
    return __builtin_amdgcn_mfma_f32_16x16x32_bf16(a, b, c, 0, 0, 0);
}

__device__ __forceinline__ void split8(float4f a, float4f b, short8& hi, short8& lo) {
#pragma unroll
    for (int j = 0; j < 4; ++j) {
        float v = a[j]; unsigned short h = f2bf(v);
        hi[j] = (short)h; lo[j] = (short)f2bf(v - bf2f(h));
        v = b[j]; h = f2bf(v);
        hi[4 + j] = (short)h; lo[4 + j] = (short)f2bf(v - bf2f(h));
    }
}

// ---- prep: W -> bf16 hi/lo planes, biases -> fp32, zero ticket ----
__global__ void k_prep(const void* __restrict__ W1, const void* __restrict__ W2,
                       const void* __restrict__ W3, const void* __restrict__ b1,
                       const void* __restrict__ b2, const void* __restrict__ b3,
                       float* __restrict__ ws) {
    const int tid = threadIdx.x, bid = blockIdx.x;
    const int isf32 = detect_f32((const unsigned short*)W1, tid & 63);
    unsigned short* whi = (unsigned short*)(ws + WS_WPLANES);
    unsigned short* wlo = whi + NWELEM;
    if (bid < 96) {
        int s = (bid * 256 + tid) * 8;        // 96*256*8 = 196608
        int mat = s >> 14, off = s & 16383;   // mat = wsel*4 + layer
        int wsel = mat >> 2;
        const void* Wm = wsel == 0 ? W1 : (wsel == 1 ? W2 : W3);
        int src = (mat & 3) * 16384 + off;
        short8 hi, lo;
        if (isf32) {
            const float* p = (const float*)Wm + src;
            split8(*(const float4f*)p, *(const float4f*)(p + 4), hi, lo);
        } else {
            hi = *(const short8*)((const unsigned short*)Wm + src);
            lo = (short8){0, 0, 0, 0, 0, 0, 0, 0};
        }
        *(short8*)(whi + s) = hi;
        *(short8*)(wlo + s) = lo;
    } else {
        for (int e = tid; e < 1536; e += 256) {
            int bsel = e >> 9, idx = e & 511;
            const void* bp = bsel == 0 ? b1 : (bsel == 1 ? b2 : b3);
            ws[WS_BIAS + e] = isf32 ? ((const float*)bp)[idx]
                                    : bf2f(((const unsigned short*)bp)[idx]);
        }
        if (tid == 0) ((int*)ws)[0] = 0;   // finalize ticket
    }
}

// Weight fragment set for one matvec: [kk]{w0h,w1h,w0l,w1l}. All static indices.
struct W8 { short8 v[16]; };
struct W8x2 { W8 a, b; };

__device__ __forceinline__ W8 loadW(const unsigned short* __restrict__ wh,
                                    const unsigned short* __restrict__ wl,
                                    int c0, int c1, int q) {
    W8 r;
#pragma unroll
    for (int kk = 0; kk < 4; ++kk) {
        const int kc = kk * 32 + q * 8;
        r.v[kk * 4 + 0] = *(const short8*)(wh + c0 * 128 + kc);
        r.v[kk * 4 + 1] = *(const short8*)(wh + c1 * 128 + kc);
        r.v[kk * 4 + 2] = *(const short8*)(wl + c0 * 128 + kc);
        r.v[kk * 4 + 3] = *(const short8*)(wl + c1 * 128 + kc);
    }
    return r;
}

// ---- single matvec (r6 form), NPREF next weight-sets prefetched after barrier.
// MODE 0: out=leaky(v) | 1: out=res+v | 2: out=leaky(v)+count | 3: count only
template<int MODE, int NPREF>
__device__ __forceinline__ W8x2 matvecS(const W8& w,
        const unsigned short* inh, const unsigned short* inl,
        unsigned short* outh, unsigned short* outl,
        const unsigned short* resh, const unsigned short* resl,
        const unsigned short* __restrict__ nah, const unsigned short* __restrict__ nal,
        const unsigned short* __restrict__ nbh, const unsigned short* __restrict__ nbl,
        const float* __restrict__ bias,
        int lane, int colb, int* cnt) {
    const int m = lane & 15, q = lane >> 4;
    const int c0 = colb + m, c1 = colb + 16 + m;
    float b0 = bias[c0], b1v = bias[c1];
    float4f acc[2][2];
#pragma unroll
    for (int rt = 0; rt < 2; ++rt) {
        acc[rt][0] = (float4f){b0, b0, b0, b0};
        acc[rt][1] = (float4f){b1v, b1v, b1v, b1v};
    }
    __syncthreads();   // prev writes visible; this interval's w loads drained
    W8x2 wn;
    wn.a = loadW(nah, nal, c0, c1, q);
    if constexpr (NPREF == 2) wn.b = loadW(nbh, nbl, c0, c1, q);
#pragma unroll
    for (int kk = 0; kk < 4; ++kk) {
        const int kc = kk * 32 + q * 8;
#pragma unroll
        for (int rt = 0; rt < 2; ++rt) {
            short8 xh = *(const short8*)(inh + (rt * 16 + m) * PITCH + kc);
            short8 xl = *(const short8*)(inl + (rt * 16 + m) * PITCH + kc);
            acc[rt][0] = mfma16(xh, w.v[kk * 4 + 0], acc[rt][0]);
            acc[rt][0] = mfma16(xl, w.v[kk * 4 + 0], acc[rt][0]);
            acc[rt][0] = mfma16(xh, w.v[kk * 4 + 2], acc[rt][0]);
            acc[rt][1] = mfma16(xh, w.v[kk * 4 + 1], acc[rt][1]);
            acc[rt][1] = mfma16(xl, w.v[kk * 4 + 1], acc[rt][1]);
            acc[rt][1] = mfma16(xh, w.v[kk * 4 + 3], acc[rt][1]);
        }
    }
    int c[2][4];
#pragma unroll
    for (int rt = 0; rt < 2; ++rt) {
#pragma unroll
        for (int r = 0; r < 4; ++r) {
            float v0 = acc[rt][0][r], v1 = acc[rt][1][r];
            int row = rt * 16 + q * 4 + r;
            int o0 = row * PITCH + c0, o1 = row * PITCH + c1;
            if (MODE == 1) {
                v0 += bf2f(resh[o0]) + bf2f(resl[o0]);
                v1 += bf2f(resh[o1]) + bf2f(resl[o1]);
            }
            if (MODE >= 2) c[rt][r] = (v0 <= 0.0f) + (v1 <= 0.0f);
            if (MODE == 0 || MODE == 2) {
                v0 = v0 > 0.0f ? v0 : 0.1f * v0;
                v1 = v1 > 0.0f ? v1 : 0.1f * v1;
            }
            if (MODE != 3) {
                unsigned short h0 = f2bf(v0);
                outh[o0] = h0; outl[o0] = f2bf(v0 - bf2f(h0));
                unsigned short h1 = f2bf(v1);
                outh[o1] = h1; outl[o1] = f2bf(v1 - bf2f(h1));
            }
        }
    }
    if (MODE >= 2) {
#pragma unroll
        for (int rt = 0; rt < 2; ++rt) {
#pragma unroll
            for (int r = 0; r < 4; ++r) {
                int cc = c[rt][r];
                cc += __shfl_xor(cc, 1);
                cc += __shfl_xor(cc, 2);
                cc += __shfl_xor(cc, 4);
                cc += __shfl_xor(cc, 8);
                if (m == 0) atomicAdd(&cnt[rt * 16 + q * 4 + r], cc);
            }
        }
    }
    return wn;
}

// ---- paired matvec: TWO independent matvecs in ONE barrier interval.
// Slot A: plain fwd (leaky out). Slot B: count pass (MODEB 2: leaky-out+count,
// MODEB 3: count only). Two independent MFMA chains + two weight sets = more
// ILP per interval; halves the serial interval count for the count chain.
template<int MODEB, int NPREF>
__device__ __forceinline__ W8x2 matvecP(const W8x2& w,
        const unsigned short* inAh, const unsigned short* inAl,
        const unsigned short* inBh, const unsigned short* inBl,
        unsigned short* outAh, unsigned short* outAl,
        unsigned short* outBh, unsigned short* outBl,
        const unsigned short* __restrict__ nah, const unsigned short* __restrict__ nal,
        const unsigned short* __restrict__ nbh, const unsigned short* __restrict__ nbl,
        const float* __restrict__ biasA, const float* __restrict__ biasB,
        int lane, int colb, int* cnt) {
    const int m = lane & 15, q = lane >> 4;
    const int c0 = colb + m, c1 = colb + 16 + m;
    float bA0 = biasA[c0], bA1 = biasA[c1];
    float bB0 = biasB[c0], bB1 = biasB[c1];
    float4f aA[2][2], aB[2][2];
#pragma unroll
    for (int rt = 0; rt < 2; ++rt) {
        aA[rt][0] = (float4f){bA0, bA0, bA0, bA0};
        aA[rt][1] = (float4f){bA1, bA1, bA1, bA1};
        aB[rt][0] = (float4f){bB0, bB0, bB0, bB0};
        aB[rt][1] = (float4f){bB1, bB1, bB1, bB1};
    }
    __syncthreads();
    W8x2 wn;
    wn.a = loadW(nah, nal, c0, c1, q);
    if constexpr (NPREF == 2) wn.b = loadW(nbh, nbl, c0, c1, q);
#pragma unroll
    for (int kk = 0; kk < 4; ++kk) {
        const int kc = kk * 32 + q * 8;
#pragma unroll
        for (int rt = 0; rt < 2; ++rt) {
            short8 xah = *(const short8*)(inAh + (rt * 16 + m) * PITCH + kc);
            short8 xal = *(const short8*)(inAl + (rt * 16 + m) * PITCH + kc);
            short8 xbh = *(const short8*)(inBh + (rt * 16 + m) * PITCH + kc);
            short8 xbl = *(const short8*)(inBl + (rt * 16 + m) * PITCH + kc);
            aA[rt][0] = mfma16(xah, w.a.v[kk * 4 + 0], aA[rt][0]);
            aB[rt][0] = mfma16(xbh, w.b.v[kk * 4 + 0], aB[rt][0]);
            aA[rt][0] = mfma16(xal, w.a.v[kk * 4 + 0], aA[rt][0]);
            aB[rt][0] = mfma16(xbl, w.b.v[kk * 4 + 0], aB[rt][0]);
            aA[rt][0] = mfma16(xah, w.a.v[kk * 4 + 2], aA[rt][0]);
            aB[rt][0] = mfma16(xbh, w.b.v[kk * 4 + 2], aB[rt][0]);
            aA[rt][1] = mfma16(xah, w.a.v[kk * 4 + 1], aA[rt][1]);
            aB[rt][1] = mfma16(xbh, w.b.v[kk * 4 + 1], aB[rt][1]);
            aA[rt][1] = mfma16(xal, w.a.v[kk * 4 + 1], aA[rt][1]);
            aB[rt][1] = mfma16(xbl, w.b.v[kk * 4 + 1], aB[rt][1]);
            aA[rt][1] = mfma16(xah, w.a.v[kk * 4 + 3], aA[rt][1]);
            aB[rt][1] = mfma16(xbh, w.b.v[kk * 4 + 3], aB[rt][1]);
        }
    }
    int c[2][4];
#pragma unroll
    for (int rt = 0; rt < 2; ++rt) {
#pragma unroll
        for (int r = 0; r < 4; ++r) {
            int row = rt * 16 + q * 4 + r;
            int o0 = row * PITCH + c0, o1 = row * PITCH + c1;
            // slot A: plain leaky fwd
            float vA0 = aA[rt][0][r], vA1 = aA[rt][1][r];
            vA0 = vA0 > 0.0f ? vA0 : 0.1f * vA0;
            vA1 = vA1 > 0.0f ? vA1 : 0.1f * vA1;
            unsigned short hA0 = f2bf(vA0);
            outAh[o0] = hA0; outAl[o0] = f2bf(vA0 - bf2f(hA0));
            unsigned short hA1 = f2bf(vA1);
            outAh[o1] = hA1; outAl[o1] = f2bf(vA1 - bf2f(hA1));
            // slot B: count (and leaky-out for MODEB==2)
            float vB0 = aB[rt][0][r], vB1 = aB[rt][1][r];
            c[rt][r] = (vB0 <= 0.0f) + (vB1 <= 0.0f);
            if (MODEB == 2) {
                vB0 = vB0 > 0.0f ? vB0 : 0.1f * vB0;
                vB1 = vB1 > 0.0f ? vB1 : 0.1f * vB1;
                unsigned short hB0 = f2bf(vB0);
                outBh[o0] = hB0; outBl[o0] = f2bf(vB0 - bf2f(hB0));
                unsigned short hB1 = f2bf(vB1);
                outBh[o1] = hB1; outBl[o1] = f2bf(vB1 - bf2f(hB1));
            }
        }
    }
#pragma unroll
    for (int rt = 0; rt < 2; ++rt) {
#pragma unroll
        for (int r = 0; r < 4; ++r) {
            int cc = c[rt][r];
            cc += __shfl_xor(cc, 1);
            cc += __shfl_xor(cc, 2);
            cc += __shfl_xor(cc, 4);
            cc += __shfl_xor(cc, 8);
            if (m == 0) atomicAdd(&cnt[rt * 16 + q * 4 + r], cc);
        }
    }
    return wn;
}

// Per-block fwd: 14 barrier intervals instead of 20 — the count chain of
// layer L (g1,g2) runs PAIRED with the forward chain of layer L+1 (both
// depend only on x_{L+1}). Planes: A/B ping-pong x; T,U temps; the dead
// x_L plane carries leaky(g1) between the two paired intervals.
template<int ISF32>
__device__ __forceinline__ void fwd(int bid, int tid, int lane, char* ldsb,
                                    const void* x, const float* ws, void* out,
                                    float* wsw) {
    unsigned short* P = (unsigned short*)ldsb;
    unsigned short* Ah = P;
    unsigned short* Al = P + 1 * ROWS * PITCH;
    unsigned short* Bh = P + 2 * ROWS * PITCH;
    unsigned short* Bl = P + 3 * ROWS * PITCH;
    unsigned short* Th = P + 4 * ROWS * PITCH;
    unsigned short* Tl = P + 5 * ROWS * PITCH;
    unsigned short* Uh = P + 6 * ROWS * PITCH;
    unsigned short* Ul = P + 7 * ROWS * PITCH;
    int* cnt = (int*)(P + 8 * ROWS * PITCH);
    const unsigned short* whi = (const unsigned short*)(ws + WS_WPLANES);
    const unsigned short* wlo = whi + NWELEM;
    const float* bias = ws + WS_BIAS;
    const int r0 = bid * ROWS;
    const int m = lane & 15, q = lane >> 4;
    const int colb = (tid >> 6) * 32;
    const int c0 = colb + m, c1 = colb + 16 + m;
    // prefetch layer-0 w1 while staging x into LDS
    W8 w10 = loadW(whi, wlo, c0, c1, q);
    for (int e = tid; e < ROWS * 128; e += 256) {
        int r = e >> 7, c = e & 127;
        float v = ldv<ISF32>(x, (r0 + r) * 128 + c);
        unsigned short h = f2bf(v);
        Ah[r * PITCH + c] = h;
        Al[r * PITCH + c] = f2bf(v - bf2f(h));
    }
    if (tid < ROWS) cnt[tid] = 0;

    // ---- prologue: layer-0 forward (3 intervals) ----
    W8x2 wc;
    wc = matvecS<0, 1>(w10, Ah, Al, Th, Tl, 0, 0,
                       whi + 4 * 16384, wlo + 4 * 16384, 0, 0,
                       bias, lane, colb, cnt);                      // h1(0)
    wc = matvecS<0, 1>(wc.a, Th, Tl, Uh, Ul, 0, 0,
                       whi + 8 * 16384, wlo + 8 * 16384, 0, 0,
                       bias + 512, lane, colb, cnt);                // h2(0)
    wc = matvecS<1, 2>(wc.a, Uh, Ul, Bh, Bl, Ah, Al,
                       whi + 1 * 16384, wlo + 1 * 16384,
                       whi + 0 * 16384, wlo + 0 * 16384,
                       bias + 1024, lane, colb, cnt);               // res(0) -> x1 in B
    unsigned short *xnh = Bh, *xnl = Bl, *ddh = Ah, *ddl = Al;
    // ---- 3 middle layers: {pair, pair, res} each ----
#pragma unroll 1
    for (int L = 0; L < 3; ++L) {
        const int Ln = L + 1, Lnn = (L < 2) ? L + 2 : 3;
        const unsigned short* w2nh = whi + (4 + Ln) * 16384;
        const unsigned short* w2nl = wlo + (4 + Ln) * 16384;
        const unsigned short* w2ch = whi + (4 + L) * 16384;
        const unsigned short* w2cl = wlo + (4 + L) * 16384;
        const unsigned short* w3nh = whi + (8 + Ln) * 16384;
        const unsigned short* w3nl = wlo + (8 + Ln) * 16384;
        const unsigned short* w1ah = whi + Lnn * 16384;
        const unsigned short* w1al = wlo + Lnn * 16384;
        const unsigned short* w1bh = whi + Ln * 16384;
        const unsigned short* w1bl = wlo + Ln * 16384;
        // pair: h1(L+1) [A: xn->T, w1[L+1]] || g1(L) count d1 [B: xn->dead, w1[L]]
        wc = matvecP<2, 2>(wc, xnh, xnl, xnh, xnl, Th, Tl, ddh, ddl,
                           w2nh, w2nl, w2ch, w2cl,
                           bias + Ln * 128, bias + L * 128, lane, colb, cnt);
        // pair: h2(L+1) [A: T->U, w2[L+1]] || g2(L) count d2 [B: dead->-, w2[L]]
        wc = matvecP<3, 1>(wc, Th, Tl, ddh, ddl, Uh, Ul, Th, Tl,
                           w3nh, w3nl, 0, 0,
                           bias + 512 + Ln * 128, bias + 512 + L * 128, lane, colb, cnt);
        // res(L+1): U -> dead (x_{L+2}), res = xn; prefetch next pair weights
        wc = matvecS<1, 2>(wc.a, Uh, Ul, ddh, ddl, xnh, xnl,
                           w1ah, w1al, w1bh, w1bl,
                           bias + 1024 + Ln * 128, lane, colb, cnt);
        unsigned short* t;
        t = xnh; xnh = ddh; ddh = t;
        t = xnl; xnl = ddl; ddl = t;
    }
    // ---- epilogue: layer-3 counts (2 intervals) ----
    wc = matvecS<2, 1>(wc.a, xnh, xnl, Th, Tl, 0, 0,
                       whi + 7 * 16384, wlo + 7 * 16384, 0, 0,
                       bias + 3 * 128, lane, colb, cnt);            // g1(3) count d1
    matvecS<3, 1>(wc.a, Th, Tl, Th, Tl, 0, 0,
                  whi + 7 * 16384, wlo + 7 * 16384, 0, 0,
                  bias + 512 + 3 * 128, lane, colb, cnt);           // g2(3) count d2
    __syncthreads();
    for (int e = tid; e < ROWS * 128; e += 256) {
        int r = e >> 7, c = e & 127;
        float v = bf2f(xnh[r * PITCH + c]) + bf2f(xnl[r * PITCH + c]);
        if (ISF32) ((float*)out)[(r0 + r) * 128 + c] = v;
        else ((unsigned short*)out)[(r0 + r) * 128 + c] = f2bf(v);
    }
    if (tid < ROWS) wsw[64 + r0 + tid] = (float)cnt[tid];
}

// ---- register-resident unpivoted LU, RANK-4 per barrier (32 intervals).
template<int ISF32>
__device__ __forceinline__ float lu_logdet(int id, int tid, float* lds,
        const void* W1, const void* W2, const void* W3) {
    const int wsel = id % 3;
    const void* Wm = (wsel == 0 ? W1 : (wsel == 1 ? W2 : W3));
    const int ofs = (id / 3) * 16384;
    const int tx = tid & 31, ty = tid >> 5;
    float* rowbuf = lds;          // [2][4][128]: rows K..K+3
    float* colbuf = lds + 1024;   // [2][4][128]: cols K..K+3 packed [j][ty*16+m]
    float4f V[16];                // A[ty+8m][4tx..4tx+3]
#pragma unroll
    for (int m = 0; m < 16; ++m) {
        int base = ofs + (ty + 8 * m) * 128 + 4 * tx;
        if (ISF32) {
            V[m] = *(const float4f*)((const float*)Wm + base);
        } else {
            ushort4 u = *(const ushort4*)((const unsigned short*)Wm + base);
            V[m] = (float4f){bf2f(u.x), bf2f(u.y), bf2f(u.z), bf2f(u.w)};
        }
    }
    if (ty < 4) *(float4f*)&rowbuf[ty * 128 + 4 * tx] = V[0];
    if (tx == 0) {
#pragma unroll
        for (int j = 0; j < 4; ++j) {
#pragma unroll
            for (int mg = 0; mg < 4; ++mg) {
                float4f t = {V[mg * 4 + 0][j], V[mg * 4 + 1][j],
                             V[mg * 4 + 2][j], V[mg * 4 + 3][j]};
                *(float4f*)&colbuf[j * 128 + ty * 16 + mg * 4] = t;
            }
        }
    }
    __syncthreads();
    float logacc = 0.0f;
#pragma unroll 1
    for (int kap = 0; kap < 32; ++kap) {
        const int K = kap * 4;
        const int buf = (kap & 1) * 512;
        float4f D[4], R[4], C[4][4];
#pragma unroll
        for (int j = 0; j < 4; ++j) {
            D[j] = *(const float4f*)&rowbuf[buf + j * 128 + K];       // broadcast
            R[j] = *(const float4f*)&rowbuf[buf + j * 128 + 4 * tx];
#pragma unroll
            for (int mg = 0; mg < 4; ++mg)
                C[j][mg] = *(const float4f*)&colbuf[buf + j * 128 + ty * 16 + mg * 4];
        }
        float p0 = D[0][0], i0 = 1.0f / p0;
        float l10 = D[1][0] * i0, l20 = D[2][0] * i0, l30 = D[3][0] * i0;
        D[1] = vmsub(D[1], l10, D[0]); R[1] = vmsub(R[1], l10, R[0]);
        D[2] = vmsub(D[2], l20, D[0]); R[2] = vmsub(R[2], l20, R[0]);
        D[3] = vmsub(D[3], l30, D[0]); R[3] = vmsub(R[3], l30, R[0]);
        float p1 = D[1][1], i1 = 1.0f / p1;
        float l21 = D[2][1] * i1, l31 = D[3][1] * i1;
        D[2] = vmsub(D[2], l21, D[1]); R[2] = vmsub(R[2], l21, R[1]);
        D[3] = vmsub(D[3], l31, D[1]); R[3] = vmsub(R[3], l31, R[1]);
        float p2 = D[2][2], i2 = 1.0f / p2;
        float l32 = D[3][2] * i2;
        D[3] = vmsub(D[3], l32, D[2]); R[3] = vmsub(R[3], l32, R[2]);
        float p3 = D[3][3], i3 = 1.0f / p3;
        logacc += __log2f(fabsf(p0)) + __log2f(fabsf(p1))
                + __log2f(fabsf(p2)) + __log2f(fabsf(p3));
        // back-substitution: X = Upanel^{-1} * R  (solve U X = R, U upper-tri)
        float4f X3 = vscale(R[3], i3);
        float4f X2 = vscale(vmsub(R[2], D[2][3], X3), i2);
        float4f X1 = vscale(vmsub(vmsub(R[1], D[1][2], X2), D[1][3], X3), i1);
        float4f X0 = vscale(vmsub(vmsub(vmsub(R[0], D[0][1], X1),
                                        D[0][2], X2), D[0][3], X3), i0);
        // rank-4 trailing update with RAW column values (no masking needed)
#pragma unroll
        for (int mg = 0; mg < 4; ++mg) {
#pragma unroll
            for (int e = 0; e < 4; ++e) {
                float4f v = V[mg * 4 + e];
                v = vmsub(v, C[0][mg][e], X0);
                v = vmsub(v, C[1][mg][e], X1);
                v = vmsub(v, C[2][mg][e], X2);
                v = vmsub(v, C[3][mg][e], X3);
                V[mg * 4 + e] = v;
            }
        }
        if (kap < 31) {
            const int nbuf = ((kap + 1) & 1) * 512;
            const int tb = (kap & 1) ? 0 : 4;
            const int mn = (kap + 1) >> 1;
            if (ty >= tb && ty < tb + 4) {
                float4f val;
                switch (mn) {
                case 0:  val = V[0];  break; case 1:  val = V[1];  break;
                case 2:  val = V[2];  break; case 3:  val = V[3];  break;
                case 4:  val = V[4];  break; case 5:  val = V[5];  break;
                case 6:  val = V[6];  break; case 7:  val = V[7];  break;
                case 8:  val = V[8];  break; case 9:  val = V[9];  break;
                case 10: val = V[10]; break; case 11: val = V[11]; break;
                case 12: val = V[12]; break; case 13: val = V[13]; break;
                case 14: val = V[14]; break; default: val = V[15]; break;
                }
                *(float4f*)&rowbuf[nbuf + (ty - tb) * 128 + 4 * tx] = val;
            }
            if (tx == kap + 1) {
#pragma unroll
                for (int j = 0; j < 4; ++j) {
#pragma unroll
                    for (int mg = 0; mg < 4; ++mg) {
                        float4f t = {V[mg * 4 + 0][j], V[mg * 4 + 1][j],
                                     V[mg * 4 + 2][j], V[mg * 4 + 3][j]};
                        *(float4f*)&colbuf[nbuf + j * 128 + ty * 16 + mg * 4] = t;
                    }
                }
            }
        }
        __syncthreads();
    }
    return logacc * LN2;
}

__global__ __launch_bounds__(256, 1) void k_main(
        const void* __restrict__ x,
        const void* __restrict__ W1, const void* __restrict__ b1,
        const void* __restrict__ W2, const void* __restrict__ b2,
        const void* __restrict__ W3, const void* __restrict__ b3,
        void* __restrict__ out, float* __restrict__ ws) {
    extern __shared__ __align__(16) char ldsb[];
    __shared__ int s_last;
    const int tid = threadIdx.x;
    const int lane = tid & 63;
    const int isf32 = detect_f32((const unsigned short*)W1, lane);

    if (blockIdx.x < 12) {
        float ld = isf32 ? lu_logdet<1>(blockIdx.x, tid, (float*)ldsb, W1, W2, W3)
                         : lu_logdet<0>(blockIdx.x, tid, (float*)ldsb, W1, W2, W3);
        if (tid == 0) ws[2 + blockIdx.x] = ld;
    } else {
        const int bid = blockIdx.x - 12;
        if (isf32) fwd<1>(bid, tid, lane, ldsb, x, ws, out, ws);
        else       fwd<0>(bid, tid, lane, ldsb, x, ws, out, ws);
    }

    // ---- last-block finalize ----
    __threadfence();
    if (tid == 0) s_last = (atomicAdd((int*)ws, 1) == NBLK - 1);
    __syncthreads();
    if (!s_last) return;
    __threadfence();   // acquire: other blocks' ws writes now visible
    float s = 0.0f;
#pragma unroll
    for (int i = 0; i < 12; ++i) s += ws[2 + i];
    for (int b = tid; b < 4096; b += 256) {
        float v = s + LOG_SLOPE * ws[64 + b];
        if (isf32) ((float*)out)[524288 + b] = v;
        else ((unsigned short*)out)[524288 + b] = f2bf(v);
    }
}

extern "C" void kernel_launch(void* const* d_in, const int* in_sizes, int n_in,
                              void* d_out, int out_size, void* d_ws, size_t ws_size,
                              hipStream_t stream) {
    const void* x  = d_in[0];
    const void* W1 = d_in[1];
    const void* b1 = d_in[2];
    const void* W2 = d_in[3];
    const void* b2 = d_in[4];
    const void* W3 = d_in[5];
    const void* b3 = d_in[6];
    float* ws = (float*)d_ws;

    hipLaunchKernelGGL(k_prep, dim3(97), dim3(256), 0, stream,
                       W1, W2, W3, b1, b2, b3, ws);
    hipLaunchKernelGGL(k_main, dim3(NBLK), dim3(256), LDS_BYTES, stream,
                       x, W1, b1, W2, b2, W3, b3, d_out, ws);
}

// Round 10
// 128.838 us; speedup vs baseline: 2.7712x; 1.0888x over previous
//
#include <hip/hip_runtime.h>

typedef __attribute__((ext_vector_type(8))) short short8;
typedef __attribute__((ext_vector_type(4))) float float4f;

#define PITCH 136   // shorts/row in LDS planes
#define ROWS 32     // rows per fwd block
#define LOG_SLOPE -2.302585092994046f   // log(0.1)
#define LN2 0.6931471805599453f
#define NBLK 140    // 12 LU + 128 fwd
#define LDS_BYTES 69760   // 8 planes * 32*136*2 + 128 cnt
// ws layout (floats): [0] ticket | [2..13] logdet partials | [64..4159] counts
// [4160..5695] fp32 biases | [8192..] W hi/lo ushort planes
#define WS_BIAS 4160
#define WS_WPLANES 8192
#define NWELEM 196608   // 12 * 16384

__device__ __forceinline__ float bf2f(unsigned int u) {
    return __builtin_bit_cast(float, u << 16);
}
__device__ __forceinline__ unsigned short f2bf(float f) {
    unsigned int x = __builtin_bit_cast(unsigned int, f);
    x += 0x7fff + ((x >> 16) & 1);   // round-to-nearest-even
    return (unsigned short)(x >> 16);
}
__device__ __forceinline__ float4f vmsub(float4f a, float s, float4f b) {
    a[0] -= s * b[0]; a[1] -= s * b[1]; a[2] -= s * b[2]; a[3] -= s * b[3];
    return a;
}
__device__ __forceinline__ float4f vscale(float4f a, float s) {
    a[0] *= s; a[1] *= s; a[2] *= s; a[3] *= s;
    return a;
}

// Barrier with LDS-only drain: orders ds_write/ds_read across waves but does
// NOT force vmcnt(0) like __syncthreads() — weight prefetch loads stay in
// flight across the barrier (T4: never drain vmcnt in the main loop). The
// compiler still inserts counted s_waitcnt vmcnt(N) before the first MFMA
// use of the loaded registers. MFMAs can't hoist above: they depend on
// post-barrier ds_reads, which the "memory" clobber orders.
__device__ __forceinline__ void bar_lgkm() {
    asm volatile("s_waitcnt lgkmcnt(0)\n\ts_barrier" ::: "memory");
}

template<int ISF32>
__device__ __forceinline__ float ldv(const void* p, int i) {
    if (ISF32) return ((const float*)p)[i];
    return bf2f(((const unsigned short*)p)[i]);
}

// Per-wave dtype sniff: fp32 weights read as u16 pairs have uniform-random
// mantissa halves; bf16 weights have exponent fields in a narrow band.
__device__ __forceinline__ int detect_f32(const unsigned short* W1u, int lane) {
    unsigned int u = W1u[lane * 2];
    unsigned int e = (u >> 7) & 0xFF;
    int bad = (e < 64) || (e > 135);
    return __ballot(bad) != 0ull;
}

__device__ __forceinline__ float4f mfma16(short8 a, short8 b, float4f c) {
    return __builtin_amdgcn_mfma_f32_16x16x32_bf16(a, b, c, 0, 0, 0);
}

__device__ __forceinline__ void split8(float4f a, float4f b, short8& hi, short8& lo) {
#pragma unroll
    for (int j = 0; j < 4; ++j) {
        float v = a[j]; unsigned short h = f2bf(v);
        hi[j] = (short)h; lo[j] = (short)f2bf(v - bf2f(h));
        v = b[j]; h = f2bf(v);
        hi[4 + j] = (short)h; lo[4 + j] = (short)f2bf(v - bf2f(h));
    }
}

// ---- prep: W -> bf16 hi/lo planes, biases -> fp32, zero ticket ----
__global__ void k_prep(const void* __restrict__ W1, const void* __restrict__ W2,
                       const void* __restrict__ W3, const void* __restrict__ b1,
                       const void* __restrict__ b2, const void* __restrict__ b3,
                       float* __restrict__ ws) {
    const int tid = threadIdx.x, bid = blockIdx.x;
    const int isf32 = detect_f32((const unsigned short*)W1, tid & 63);
    unsigned short* whi = (unsigned short*)(ws + WS_WPLANES);
    unsigned short* wlo = whi + NWELEM;
    if (bid < 96) {
        int s = (bid * 256 + tid) * 8;        // 96*256*8 = 196608
        int mat = s >> 14, off = s & 16383;   // mat = wsel*4 + layer
        int wsel = mat >> 2;
        const void* Wm = wsel == 0 ? W1 : (wsel == 1 ? W2 : W3);
        int src = (mat & 3) * 16384 + off;
        short8 hi, lo;
        if (isf32) {
            const float* p = (const float*)Wm + src;
            split8(*(const float4f*)p, *(const float4f*)(p + 4), hi, lo);
        } else {
            hi = *(const short8*)((const unsigned short*)Wm + src);
            lo = (short8){0, 0, 0, 0, 0, 0, 0, 0};
        }
        *(short8*)(whi + s) = hi;
        *(short8*)(wlo + s) = lo;
    } else {
        for (int e = tid; e < 1536; e += 256) {
            int bsel = e >> 9, idx = e & 511;
            const void* bp = bsel == 0 ? b1 : (bsel == 1 ? b2 : b3);
            ws[WS_BIAS + e] = isf32 ? ((const float*)bp)[idx]
                                    : bf2f(((const unsigned short*)bp)[idx]);
        }
        if (tid == 0) ((int*)ws)[0] = 0;   // finalize ticket
    }
}

// Weight fragment set for one matvec: [kk]{w0h,w1h,w0l,w1l}. All static indices.
struct W8 { short8 v[16]; };

__device__ __forceinline__ W8 loadW(const unsigned short* __restrict__ wh,
                                    const unsigned short* __restrict__ wl,
                                    int c0, int c1, int q) {
    W8 r;
#pragma unroll
    for (int kk = 0; kk < 4; ++kk) {
        const int kc = kk * 32 + q * 8;
        r.v[kk * 4 + 0] = *(const short8*)(wh + c0 * 128 + kc);
        r.v[kk * 4 + 1] = *(const short8*)(wh + c1 * 128 + kc);
        r.v[kk * 4 + 2] = *(const short8*)(wl + c0 * 128 + kc);
        r.v[kk * 4 + 3] = *(const short8*)(wl + c1 * 128 + kc);
    }
    return r;
}

// out[ROWS x 128] = act( in[ROWS x 128] @ W^T + bias ); ping-pong planes,
// one lgkm-barrier per matvec. The weight set for THIS matvec (`w`) was
// loaded >=1 interval ago. DOLOAD=1: prefetch a new set (returned) for a
// FUTURE interval; DOLOAD=0: no load this interval (the r10 change — g1/g2
// reuse the held w1/w2 sets, cutting per-block weight traffic 40%).
// MODE 0: out = leaky(v) | 1: out = res + v | 2: out = leaky(v)+count | 3: count only
template<int MODE, int DOLOAD>
__device__ __forceinline__ W8 matvec(const W8& w,
        const unsigned short* inh, const unsigned short* inl,
        unsigned short* outh, unsigned short* outl,
        const unsigned short* resh, const unsigned short* resl,
        const unsigned short* __restrict__ nwh, const unsigned short* __restrict__ nwl,
        const float* __restrict__ bias,
        int lane, int colb, int* cnt) {
    const int m = lane & 15, q = lane >> 4;
    const int c0 = colb + m, c1 = colb + 16 + m;
    float b0 = bias[c0], b1v = bias[c1];
    float4f acc[2][2];
#pragma unroll
    for (int rt = 0; rt < 2; ++rt) {
        acc[rt][0] = (float4f){b0, b0, b0, b0};
        acc[rt][1] = (float4f){b1v, b1v, b1v, b1v};
    }
    bar_lgkm();   // previous matvec's LDS writes visible; vmcnt NOT drained
    W8 wn;
    if constexpr (DOLOAD) {
        wn = loadW(nwh, nwl, c0, c1, q);   // prefetch a future weight set
    }
#pragma unroll
    for (int kk = 0; kk < 4; ++kk) {
        const int kc = kk * 32 + q * 8;
#pragma unroll
        for (int rt = 0; rt < 2; ++rt) {
            short8 xh = *(const short8*)(inh + (rt * 16 + m) * PITCH + kc);
            short8 xl = *(const short8*)(inl + (rt * 16 + m) * PITCH + kc);
            acc[rt][0] = mfma16(xh, w.v[kk * 4 + 0], acc[rt][0]);
            acc[rt][0] = mfma16(xl, w.v[kk * 4 + 0], acc[rt][0]);
            acc[rt][0] = mfma16(xh, w.v[kk * 4 + 2], acc[rt][0]);
            acc[rt][1] = mfma16(xh, w.v[kk * 4 + 1], acc[rt][1]);
            acc[rt][1] = mfma16(xl, w.v[kk * 4 + 1], acc[rt][1]);
            acc[rt][1] = mfma16(xh, w.v[kk * 4 + 3], acc[rt][1]);
        }
    }
    int c[2][4];
#pragma unroll
    for (int rt = 0; rt < 2; ++rt) {
#pragma unroll
        for (int r = 0; r < 4; ++r) {
            float v0 = acc[rt][0][r], v1 = acc[rt][1][r];
            int row = rt * 16 + q * 4 + r;
            int o0 = row * PITCH + c0, o1 = row * PITCH + c1;
            if (MODE == 1) {
                v0 += bf2f(resh[o0]) + bf2f(resl[o0]);
                v1 += bf2f(resh[o1]) + bf2f(resl[o1]);
            }
            if (MODE >= 2) c[rt][r] = (v0 <= 0.0f) + (v1 <= 0.0f);
            if (MODE == 0 || MODE == 2) {
                v0 = v0 > 0.0f ? v0 : 0.1f * v0;
                v1 = v1 > 0.0f ? v1 : 0.1f * v1;
            }
            if (MODE != 3) {
                unsigned short h0 = f2bf(v0);
                outh[o0] = h0; outl[o0] = f2bf(v0 - bf2f(h0));
                unsigned short h1 = f2bf(v1);
                outh[o1] = h1; outl[o1] = f2bf(v1 - bf2f(h1));
            }
        }
    }
    if (MODE >= 2) {
#pragma unroll
        for (int rt = 0; rt < 2; ++rt) {
#pragma unroll
            for (int r = 0; r < 4; ++r) {
                int cc = c[rt][r];
                cc += __shfl_xor(cc, 1);
                cc += __shfl_xor(cc, 2);
                cc += __shfl_xor(cc, 4);
                cc += __shfl_xor(cc, 8);
                if (m == 0) atomicAdd(&cnt[rt * 16 + q * 4 + r], cc);
            }
        }
    }
    if constexpr (DOLOAD) return wn;
    else return w;   // unused by callers; keeps a defined value
}

// Per-layer weight-set ledger (each W8 = 64 VGPR, max 3 live = 192):
//   h1  uses A=w1[L],  loads B=w2[L]
//   h2  uses B=w2[L],  loads C=w3[L]
//   res uses C=w3[L],  no load
//   g1  uses A (HELD), no load
//   g2  uses B (HELD), loads A=w1[L+1]
// 3 loads/layer instead of 5 -> per-block weight traffic 1.28MB -> 0.77MB.
template<int ISF32>
__device__ __forceinline__ void fwd(int bid, int tid, int lane, char* ldsb,
                                    const void* x, const float* ws, void* out,
                                    float* wsw) {
    unsigned short* P = (unsigned short*)ldsb;
    unsigned short* Ah = P;
    unsigned short* Al = P + 1 * ROWS * PITCH;
    unsigned short* Bh = P + 2 * ROWS * PITCH;
    unsigned short* Bl = P + 3 * ROWS * PITCH;
    unsigned short* Th = P + 4 * ROWS * PITCH;
    unsigned short* Tl = P + 5 * ROWS * PITCH;
    unsigned short* Uh = P + 6 * ROWS * PITCH;
    unsigned short* Ul = P + 7 * ROWS * PITCH;
    int* cnt = (int*)(P + 8 * ROWS * PITCH);
    const unsigned short* whi = (const unsigned short*)(ws + WS_WPLANES);
    const unsigned short* wlo = whi + NWELEM;
    const float* bias = ws + WS_BIAS;
    const int r0 = bid * ROWS;
    const int m = lane & 15, q = lane >> 4;
    const int colb = (tid >> 6) * 32;
    const int c0 = colb + m, c1 = colb + 16 + m;
    // prefetch layer-0 w1 while staging x into LDS
    W8 wA = loadW(whi, wlo, c0, c1, q);
    W8 wB, wC;
    for (int e = tid; e < ROWS * 128; e += 256) {
        int r = e >> 7, c = e & 127;
        float v = ldv<ISF32>(x, (r0 + r) * 128 + c);
        unsigned short h = f2bf(v);
        Ah[r * PITCH + c] = h;
        Al[r * PITCH + c] = f2bf(v - bf2f(h));
    }
    if (tid < ROWS) cnt[tid] = 0;
    unsigned short *curh = Ah, *curl = Al, *othh = Bh, *othl = Bl;
#pragma unroll 1
    for (int layer = 0; layer < 4; ++layer) {
        const unsigned short* w2h = whi + (4 + layer) * 16384;
        const unsigned short* w2l = wlo + (4 + layer) * 16384;
        const unsigned short* w3h = whi + (8 + layer) * 16384;
        const unsigned short* w3l = wlo + (8 + layer) * 16384;
        const unsigned short* n1h = whi + ((layer + 1) & 3) * 16384;  // next-layer w1
        const unsigned short* n1l = wlo + ((layer + 1) & 3) * 16384;
        const float* b1p = bias + layer * 128;
        const float* b2p = bias + 512 + layer * 128;
        const float* b3p = bias + 1024 + layer * 128;
        wB = matvec<0, 1>(wA, curh, curl, Th, Tl, 0, 0, w2h, w2l, b1p, lane, colb, cnt);
        wC = matvec<0, 1>(wB, Th, Tl, Uh, Ul, 0, 0, w3h, w3l, b2p, lane, colb, cnt);
        matvec<1, 0>(wC, Uh, Ul, othh, othl, curh, curl, 0, 0, b3p, lane, colb, cnt);
        matvec<2, 0>(wA, othh, othl, Th, Tl, 0, 0, 0, 0, b1p, lane, colb, cnt);
        wA = matvec<3, 1>(wB, Th, Tl, Th, Tl, 0, 0, n1h, n1l, b2p, lane, colb, cnt);
        unsigned short* t;
        t = curh; curh = othh; othh = t;
        t = curl; curl = othl; othl = t;
    }
    bar_lgkm();
    for (int e = tid; e < ROWS * 128; e += 256) {
        int r = e >> 7, c = e & 127;
        float v = bf2f(curh[r * PITCH + c]) + bf2f(curl[r * PITCH + c]);
        if (ISF32) ((float*)out)[(r0 + r) * 128 + c] = v;
        else ((unsigned short*)out)[(r0 + r) * 128 + c] = f2bf(v);
    }
    if (tid < ROWS) wsw[64 + r0 + tid] = (float)cnt[tid];
}

// ---- register-resident unpivoted LU, RANK-4 per barrier (32 intervals).
// Trailing update via V -= C_raw * (Upanel^{-1} R) (r6 identity).
template<int ISF32>
__device__ __forceinline__ float lu_logdet(int id, int tid, float* lds,
        const void* W1, const void* W2, const void* W3) {
    const int wsel = id % 3;
    const void* Wm = (wsel == 0 ? W1 : (wsel == 1 ? W2 : W3));
    const int ofs = (id / 3) * 16384;
    const int tx = tid & 31, ty = tid >> 5;
    float* rowbuf = lds;          // [2][4][128]: rows K..K+3
    float* colbuf = lds + 1024;   // [2][4][128]: cols K..K+3 packed [j][ty*16+m]
    float4f V[16];                // A[ty+8m][4tx..4tx+3]
#pragma unroll
    for (int m = 0; m < 16; ++m) {
        int base = ofs + (ty + 8 * m) * 128 + 4 * tx;
        if (ISF32) {
            V[m] = *(const float4f*)((const float*)Wm + base);
        } else {
            ushort4 u = *(const ushort4*)((const unsigned short*)Wm + base);
            V[m] = (float4f){bf2f(u.x), bf2f(u.y), bf2f(u.z), bf2f(u.w)};
        }
    }
    if (ty < 4) *(float4f*)&rowbuf[ty * 128 + 4 * tx] = V[0];
    if (tx == 0) {
#pragma unroll
        for (int j = 0; j < 4; ++j) {
#pragma unroll
            for (int mg = 0; mg < 4; ++mg) {
                float4f t = {V[mg * 4 + 0][j], V[mg * 4 + 1][j],
                             V[mg * 4 + 2][j], V[mg * 4 + 3][j]};
                *(float4f*)&colbuf[j * 128 + ty * 16 + mg * 4] = t;
            }
        }
    }
    __syncthreads();
    float logacc = 0.0f;
#pragma unroll 1
    for (int kap = 0; kap < 32; ++kap) {
        const int K = kap * 4;
        const int buf = (kap & 1) * 512;
        float4f D[4], R[4], C[4][4];
#pragma unroll
        for (int j = 0; j < 4; ++j) {
            D[j] = *(const float4f*)&rowbuf[buf + j * 128 + K];       // broadcast
            R[j] = *(const float4f*)&rowbuf[buf + j * 128 + 4 * tx];
#pragma unroll
            for (int mg = 0; mg < 4; ++mg)
                C[j][mg] = *(const float4f*)&colbuf[buf + j * 128 + ty * 16 + mg * 4];
        }
        float p0 = D[0][0], i0 = 1.0f / p0;
        float l10 = D[1][0] * i0, l20 = D[2][0] * i0, l30 = D[3][0] * i0;
        D[1] = vmsub(D[1], l10, D[0]); R[1] = vmsub(R[1], l10, R[0]);
        D[2] = vmsub(D[2], l20, D[0]); R[2] = vmsub(R[2], l20, R[0]);
        D[3] = vmsub(D[3], l30, D[0]); R[3] = vmsub(R[3], l30, R[0]);
        float p1 = D[1][1], i1 = 1.0f / p1;
        float l21 = D[2][1] * i1, l31 = D[3][1] * i1;
        D[2] = vmsub(D[2], l21, D[1]); R[2] = vmsub(R[2], l21, R[1]);
        D[3] = vmsub(D[3], l31, D[1]); R[3] = vmsub(R[3], l31, R[1]);
        float p2 = D[2][2], i2 = 1.0f / p2;
        float l32 = D[3][2] * i2;
        D[3] = vmsub(D[3], l32, D[2]); R[3] = vmsub(R[3], l32, R[2]);
        float p3 = D[3][3], i3 = 1.0f / p3;
        logacc += __log2f(fabsf(p0)) + __log2f(fabsf(p1))
                + __log2f(fabsf(p2)) + __log2f(fabsf(p3));
        float4f X3 = vscale(R[3], i3);
        float4f X2 = vscale(vmsub(R[2], D[2][3], X3), i2);
        float4f X1 = vscale(vmsub(vmsub(R[1], D[1][2], X2), D[1][3], X3), i1);
        float4f X0 = vscale(vmsub(vmsub(vmsub(R[0], D[0][1], X1),
                                        D[0][2], X2), D[0][3], X3), i0);
#pragma unroll
        for (int mg = 0; mg < 4; ++mg) {
#pragma unroll
            for (int e = 0; e < 4; ++e) {
                float4f v = V[mg * 4 + e];
                v = vmsub(v, C[0][mg][e], X0);
                v = vmsub(v, C[1][mg][e], X1);
                v = vmsub(v, C[2][mg][e], X2);
                v = vmsub(v, C[3][mg][e], X3);
                V[mg * 4 + e] = v;
            }
        }
        if (kap < 31) {
            const int nbuf = ((kap + 1) & 1) * 512;
            const int tb = (kap & 1) ? 0 : 4;
            const int mn = (kap + 1) >> 1;
            if (ty >= tb && ty < tb + 4) {
                float4f val;
                switch (mn) {
                case 0:  val = V[0];  break; case 1:  val = V[1];  break;
                case 2:  val = V[2];  break; case 3:  val = V[3];  break;
                case 4:  val = V[4];  break; case 5:  val = V[5];  break;
                case 6:  val = V[6];  break; case 7:  val = V[7];  break;
                case 8:  val = V[8];  break; case 9:  val = V[9];  break;
                case 10: val = V[10]; break; case 11: val = V[11]; break;
                case 12: val = V[12]; break; case 13: val = V[13]; break;
                case 14: val = V[14]; break; default: val = V[15]; break;
                }
                *(float4f*)&rowbuf[nbuf + (ty - tb) * 128 + 4 * tx] = val;
            }
            if (tx == kap + 1) {
#pragma unroll
                for (int j = 0; j < 4; ++j) {
#pragma unroll
                    for (int mg = 0; mg < 4; ++mg) {
                        float4f t = {V[mg * 4 + 0][j], V[mg * 4 + 1][j],
                                     V[mg * 4 + 2][j], V[mg * 4 + 3][j]};
                        *(float4f*)&colbuf[nbuf + j * 128 + ty * 16 + mg * 4] = t;
                    }
                }
            }
        }
        __syncthreads();
    }
    return logacc * LN2;
}

__global__ __launch_bounds__(256, 1) void k_main(
        const void* __restrict__ x,
        const void* __restrict__ W1, const void* __restrict__ b1,
        const void* __restrict__ W2, const void* __restrict__ b2,
        const void* __restrict__ W3, const void* __restrict__ b3,
        void* __restrict__ out, float* __restrict__ ws) {
    extern __shared__ __align__(16) char ldsb[];
    __shared__ int s_last;
    const int tid = threadIdx.x;
    const int lane = tid & 63;
    const int isf32 = detect_f32((const unsigned short*)W1, lane);

    if (blockIdx.x < 12) {
        float ld = isf32 ? lu_logdet<1>(blockIdx.x, tid, (float*)ldsb, W1, W2, W3)
                         : lu_logdet<0>(blockIdx.x, tid, (float*)ldsb, W1, W2, W3);
        if (tid == 0) ws[2 + blockIdx.x] = ld;
    } else {
        const int bid = blockIdx.x - 12;
        if (isf32) fwd<1>(bid, tid, lane, ldsb, x, ws, out, ws);
        else       fwd<0>(bid, tid, lane, ldsb, x, ws, out, ws);
    }

    // ---- last-block finalize ----
    __threadfence();
    if (tid == 0) s_last = (atomicAdd((int*)ws, 1) == NBLK - 1);
    __syncthreads();
    if (!s_last) return;
    __threadfence();   // acquire: other blocks' ws writes now visible
    float s = 0.0f;
#pragma unroll
    for (int i = 0; i < 12; ++i) s += ws[2 + i];
    for (int b = tid; b < 4096; b += 256) {
        float v = s + LOG_SLOPE * ws[64 + b];
        if (isf32) ((float*)out)[524288 + b] = v;
        else ((unsigned short*)out)[524288 + b] = f2bf(v);
    }
}

extern "C" void kernel_launch(void* const* d_in, const int* in_sizes, int n_in,
                              void* d_out, int out_size, void* d_ws, size_t ws_size,
                              hipStream_t stream) {
    const void* x  = d_in[0];
    const void* W1 = d_in[1];
    const void* b1 = d_in[2];
    const void* W2 = d_in[3];
    const void* b2 = d_in[4];
    const void* W3 = d_in[5];
    const void* b3 = d_in[6];
    float* ws = (float*)d_ws;

    hipLaunchKernelGGL(k_prep, dim3(97), dim3(256), 0, stream,
                       W1, W2, W3, b1, b2, b3, ws);
    hipLaunchKernelGGL(k_main, dim3(NBLK), dim3(256), LDS_BYTES, stream,
                       x, W1, b1, W2, b2, W3, b3, d_out, ws);
}

// Round 11
// 123.095 us; speedup vs baseline: 2.9004x; 1.0467x over previous
//
#include <hip/hip_runtime.h>

typedef __attribute__((ext_vector_type(8))) short short8;
typedef __attribute__((ext_vector_type(4))) float float4f;

#define PITCH 136   // shorts/row in LDS planes
#define ROWS 32     // rows per fwd block
#define LOG_SLOPE -2.302585092994046f   // log(0.1)
#define LN2 0.6931471805599453f
#define NBLK 140    // 12 LU + 128 fwd
#define LDS_BYTES 69760   // 8 planes * 32*136*2 + 128 cnt
// ws layout (floats): [0] ticket | [2..13] logdet partials | [64..4159] counts
// [4160..5695] fp32 biases | [8192..] W hi/lo ushort planes (TILED layout, r11)
#define WS_BIAS 4160
#define WS_WPLANES 8192
#define NWELEM 196608   // 12 * 16384

__device__ __forceinline__ float bf2f(unsigned int u) {
    return __builtin_bit_cast(float, u << 16);
}
__device__ __forceinline__ unsigned short f2bf(float f) {
    unsigned int x = __builtin_bit_cast(unsigned int, f);
    x += 0x7fff + ((x >> 16) & 1);   // round-to-nearest-even
    return (unsigned short)(x >> 16);
}
__device__ __forceinline__ float4f vmsub(float4f a, float s, float4f b) {
    a[0] -= s * b[0]; a[1] -= s * b[1]; a[2] -= s * b[2]; a[3] -= s * b[3];
    return a;
}
__device__ __forceinline__ float4f vscale(float4f a, float s) {
    a[0] *= s; a[1] *= s; a[2] *= s; a[3] *= s;
    return a;
}

// Barrier with LDS-only drain (r10): orders ds_write/ds_read across waves but
// does NOT force vmcnt(0) — weight prefetch loads stay in flight across the
// barrier; compiler inserts counted vmcnt before first use.
__device__ __forceinline__ void bar_lgkm() {
    asm volatile("s_waitcnt lgkmcnt(0)\n\ts_barrier" ::: "memory");
}

template<int ISF32>
__device__ __forceinline__ float ldv(const void* p, int i) {
    if (ISF32) return ((const float*)p)[i];
    return bf2f(((const unsigned short*)p)[i]);
}

// Per-wave dtype sniff: fp32 weights read as u16 pairs have uniform-random
// mantissa halves; bf16 weights have exponent fields in a narrow band.
__device__ __forceinline__ int detect_f32(const unsigned short* W1u, int lane) {
    unsigned int u = W1u[lane * 2];
    unsigned int e = (u >> 7) & 0xFF;
    int bad = (e < 64) || (e > 135);
    return __ballot(bad) != 0ull;
}

__device__ __forceinline__ float4f mfma16(short8 a, short8 b, float4f c) {
    return __builtin_amdgcn_mfma_f32_16x16x32_bf16(a, b, c, 0, 0, 0);
}

__device__ __forceinline__ void split8(float4f a, float4f b, short8& hi, short8& lo) {
#pragma unroll
    for (int j = 0; j < 4; ++j) {
        float v = a[j]; unsigned short h = f2bf(v);
        hi[j] = (short)h; lo[j] = (short)f2bf(v - bf2f(h));
        v = b[j]; h = f2bf(v);
        hi[4 + j] = (short)h; lo[4 + j] = (short)f2bf(v - bf2f(h));
    }
}

// ---- prep: W -> bf16 hi/lo planes (TILED: one wave's loadW instruction reads
// one contiguous 1KB block), biases -> fp32, zero ticket.
// r11: the old row-major plane made each loadW instruction touch 16 SCATTERED
// 64B lines (lanes stride 256B) -> ~16 TA transactions/inst; measured cost
// ~28ns per weight-KB per block. Tiled layout: element (c,k) of a matrix ->
// newoff = kk*4096 + cb*512 + m*32 + q*8 + k%8  (kk=k/32, q=(k%32)/8,
// cb=c/16, m=c%16). loadW's 64 lanes then cover [base, base+1KB) exactly.
__global__ void k_prep(const void* __restrict__ W1, const void* __restrict__ W2,
                       const void* __restrict__ W3, const void* __restrict__ b1,
                       const void* __restrict__ b2, const void* __restrict__ b3,
                       float* __restrict__ ws) {
    const int tid = threadIdx.x, bid = blockIdx.x;
    const int isf32 = detect_f32((const unsigned short*)W1, tid & 63);
    unsigned short* whi = (unsigned short*)(ws + WS_WPLANES);
    unsigned short* wlo = whi + NWELEM;
    if (bid < 96) {
        int s = (bid * 256 + tid) * 8;        // 96*256*8 = 196608
        int mat = s >> 14, off = s & 16383;   // mat = wsel*4 + layer
        int wsel = mat >> 2;
        const void* Wm = wsel == 0 ? W1 : (wsel == 1 ? W2 : W3);
        int src = (mat & 3) * 16384 + off;
        short8 hi, lo;
        if (isf32) {
            const float* p = (const float*)Wm + src;
            split8(*(const float4f*)p, *(const float4f*)(p + 4), hi, lo);
        } else {
            hi = *(const short8*)((const unsigned short*)Wm + src);
            lo = (short8){0, 0, 0, 0, 0, 0, 0, 0};
        }
        // tiled destination offset (8-short chunk: fixed c, k..k+7)
        int c = off >> 7, k = off & 127;
        int kk = k >> 5, q = (k >> 3) & 3;
        int cb = c >> 4, m = c & 15;
        int noff = kk * 4096 + cb * 512 + m * 32 + q * 8;
        *(short8*)(whi + mat * 16384 + noff) = hi;
        *(short8*)(wlo + mat * 16384 + noff) = lo;
    } else {
        for (int e = tid; e < 1536; e += 256) {
            int bsel = e >> 9, idx = e & 511;
            const void* bp = bsel == 0 ? b1 : (bsel == 1 ? b2 : b3);
            ws[WS_BIAS + e] = isf32 ? ((const float*)bp)[idx]
                                    : bf2f(((const unsigned short*)bp)[idx]);
        }
        if (tid == 0) ((int*)ws)[0] = 0;   // finalize ticket
    }
}

// Weight fragment set for one matvec: [kk]{w0h,w1h,w0l,w1l}. All static indices.
struct W8 { short8 v[16]; };

// Tiled-layout load: per instruction, 64 lanes cover one contiguous 1KB block.
// cb = colb/16 (even), mq = m*32 + q*8 (shorts within a 512-short block).
__device__ __forceinline__ W8 loadW(const unsigned short* __restrict__ wh,
                                    const unsigned short* __restrict__ wl,
                                    int cb, int mq) {
    W8 r;
#pragma unroll
    for (int kk = 0; kk < 4; ++kk) {
        const int o0 = kk * 4096 + cb * 512 + mq;
        const int o1 = o0 + 512;
        r.v[kk * 4 + 0] = *(const short8*)(wh + o0);
        r.v[kk * 4 + 1] = *(const short8*)(wh + o1);
        r.v[kk * 4 + 2] = *(const short8*)(wl + o0);
        r.v[kk * 4 + 3] = *(const short8*)(wl + o1);
    }
    return r;
}

// out[ROWS x 128] = act( in[ROWS x 128] @ W^T + bias ); ping-pong planes,
// one lgkm-barrier per matvec. Weight set `w` loaded >=1 interval ago.
// DOLOAD=1: prefetch a future set (returned); DOLOAD=0: no load (g1/g2 reuse
// held w1/w2 sets -- r10, cuts weight traffic 40%).
// MODE 0: out = leaky(v) | 1: out = res + v | 2: out = leaky(v)+count | 3: count only
template<int MODE, int DOLOAD>
__device__ __forceinline__ W8 matvec(const W8& w,
        const unsigned short* inh, const unsigned short* inl,
        unsigned short* outh, unsigned short* outl,
        const unsigned short* resh, const unsigned short* resl,
        const unsigned short* __restrict__ nwh, const unsigned short* __restrict__ nwl,
        const float* __restrict__ bias,
        int lane, int colb, int* cnt) {
    const int m = lane & 15, q = lane >> 4;
    const int c0 = colb + m, c1 = colb + 16 + m;
    float b0 = bias[c0], b1v = bias[c1];
    float4f acc[2][2];
#pragma unroll
    for (int rt = 0; rt < 2; ++rt) {
        acc[rt][0] = (float4f){b0, b0, b0, b0};
        acc[rt][1] = (float4f){b1v, b1v, b1v, b1v};
    }
    bar_lgkm();   // previous matvec's LDS writes visible; vmcnt NOT drained
    W8 wn;
    if constexpr (DOLOAD) {
        wn = loadW(nwh, nwl, colb >> 4, m * 32 + q * 8);   // coalesced prefetch
    }
#pragma unroll
    for (int kk = 0; kk < 4; ++kk) {
        const int kc = kk * 32 + q * 8;
#pragma unroll
        for (int rt = 0; rt < 2; ++rt) {
            short8 xh = *(const short8*)(inh + (rt * 16 + m) * PITCH + kc);
            short8 xl = *(const short8*)(inl + (rt * 16 + m) * PITCH + kc);
            acc[rt][0] = mfma16(xh, w.v[kk * 4 + 0], acc[rt][0]);
            acc[rt][0] = mfma16(xl, w.v[kk * 4 + 0], acc[rt][0]);
            acc[rt][0] = mfma16(xh, w.v[kk * 4 + 2], acc[rt][0]);
            acc[rt][1] = mfma16(xh, w.v[kk * 4 + 1], acc[rt][1]);
            acc[rt][1] = mfma16(xl, w.v[kk * 4 + 1], acc[rt][1]);
            acc[rt][1] = mfma16(xh, w.v[kk * 4 + 3], acc[rt][1]);
        }
    }
    int c[2][4];
#pragma unroll
    for (int rt = 0; rt < 2; ++rt) {
#pragma unroll
        for (int r = 0; r < 4; ++r) {
            float v0 = acc[rt][0][r], v1 = acc[rt][1][r];
            int row = rt * 16 + q * 4 + r;
            int o0 = row * PITCH + c0, o1 = row * PITCH + c1;
            if (MODE == 1) {
                v0 += bf2f(resh[o0]) + bf2f(resl[o0]);
                v1 += bf2f(resh[o1]) + bf2f(resl[o1]);
            }
            if (MODE >= 2) c[rt][r] = (v0 <= 0.0f) + (v1 <= 0.0f);
            if (MODE == 0 || MODE == 2) {
                v0 = v0 > 0.0f ? v0 : 0.1f * v0;
                v1 = v1 > 0.0f ? v1 : 0.1f * v1;
            }
            if (MODE != 3) {
                unsigned short h0 = f2bf(v0);
                outh[o0] = h0; outl[o0] = f2bf(v0 - bf2f(h0));
                unsigned short h1 = f2bf(v1);
                outh[o1] = h1; outl[o1] = f2bf(v1 - bf2f(h1));
            }
        }
    }
    if (MODE >= 2) {
#pragma unroll
        for (int rt = 0; rt < 2; ++rt) {
#pragma unroll
            for (int r = 0; r < 4; ++r) {
                int cc = c[rt][r];
                cc += __shfl_xor(cc, 1);
                cc += __shfl_xor(cc, 2);
                cc += __shfl_xor(cc, 4);
                cc += __shfl_xor(cc, 8);
                if (m == 0) atomicAdd(&cnt[rt * 16 + q * 4 + r], cc);
            }
        }
    }
    if constexpr (DOLOAD) return wn;
    else return w;   // unused by callers; keeps a defined value
}

// Per-layer weight-set ledger (each W8 = 64 VGPR, max 3 live = 192):
//   h1 uses A=w1[L], loads B=w2[L] | h2 uses B, loads C=w3[L] | res uses C
//   g1 uses A (HELD) | g2 uses B (HELD), loads A=w1[L+1]
// 3 loads/layer instead of 5 -> per-block weight traffic 1.28MB -> 0.77MB.
template<int ISF32>
__device__ __forceinline__ void fwd(int bid, int tid, int lane, char* ldsb,
                                    const void* x, const float* ws, void* out,
                                    float* wsw) {
    unsigned short* P = (unsigned short*)ldsb;
    unsigned short* Ah = P;
    unsigned short* Al = P + 1 * ROWS * PITCH;
    unsigned short* Bh = P + 2 * ROWS * PITCH;
    unsigned short* Bl = P + 3 * ROWS * PITCH;
    unsigned short* Th = P + 4 * ROWS * PITCH;
    unsigned short* Tl = P + 5 * ROWS * PITCH;
    unsigned short* Uh = P + 6 * ROWS * PITCH;
    unsigned short* Ul = P + 7 * ROWS * PITCH;
    int* cnt = (int*)(P + 8 * ROWS * PITCH);
    const unsigned short* whi = (const unsigned short*)(ws + WS_WPLANES);
    const unsigned short* wlo = whi + NWELEM;
    const float* bias = ws + WS_BIAS;
    const int r0 = bid * ROWS;
    const int m = lane & 15, q = lane >> 4;
    const int colb = (tid >> 6) * 32;
    // prefetch layer-0 w1 while staging x into LDS
    W8 wA = loadW(whi, wlo, colb >> 4, m * 32 + q * 8);
    W8 wB, wC;
    for (int e = tid; e < ROWS * 128; e += 256) {
        int r = e >> 7, c = e & 127;
        float v = ldv<ISF32>(x, (r0 + r) * 128 + c);
        unsigned short h = f2bf(v);
        Ah[r * PITCH + c] = h;
        Al[r * PITCH + c] = f2bf(v - bf2f(h));
    }
    if (tid < ROWS) cnt[tid] = 0;
    unsigned short *curh = Ah, *curl = Al, *othh = Bh, *othl = Bl;
#pragma unroll 1
    for (int layer = 0; layer < 4; ++layer) {
        const unsigned short* w2h = whi + (4 + layer) * 16384;
        const unsigned short* w2l = wlo + (4 + layer) * 16384;
        const unsigned short* w3h = whi + (8 + layer) * 16384;
        const unsigned short* w3l = wlo + (8 + layer) * 16384;
        const unsigned short* n1h = whi + ((layer + 1) & 3) * 16384;  // next-layer w1
        const unsigned short* n1l = wlo + ((layer + 1) & 3) * 16384;
        const float* b1p = bias + layer * 128;
        const float* b2p = bias + 512 + layer * 128;
        const float* b3p = bias + 1024 + layer * 128;
        wB = matvec<0, 1>(wA, curh, curl, Th, Tl, 0, 0, w2h, w2l, b1p, lane, colb, cnt);
        wC = matvec<0, 1>(wB, Th, Tl, Uh, Ul, 0, 0, w3h, w3l, b2p, lane, colb, cnt);
        matvec<1, 0>(wC, Uh, Ul, othh, othl, curh, curl, 0, 0, b3p, lane, colb, cnt);
        matvec<2, 0>(wA, othh, othl, Th, Tl, 0, 0, 0, 0, b1p, lane, colb, cnt);
        wA = matvec<3, 1>(wB, Th, Tl, Th, Tl, 0, 0, n1h, n1l, b2p, lane, colb, cnt);
        unsigned short* t;
        t = curh; curh = othh; othh = t;
        t = curl; curl = othl; othl = t;
    }
    bar_lgkm();
    for (int e = tid; e < ROWS * 128; e += 256) {
        int r = e >> 7, c = e & 127;
        float v = bf2f(curh[r * PITCH + c]) + bf2f(curl[r * PITCH + c]);
        if (ISF32) ((float*)out)[(r0 + r) * 128 + c] = v;
        else ((unsigned short*)out)[(r0 + r) * 128 + c] = f2bf(v);
    }
    if (tid < ROWS) wsw[64 + r0 + tid] = (float)cnt[tid];
}

// ---- register-resident unpivoted LU, RANK-4 per barrier (32 intervals).
// Trailing update via V -= C_raw * (Upanel^{-1} R) (r6 identity). Reads raw W.
template<int ISF32>
__device__ __forceinline__ float lu_logdet(int id, int tid, float* lds,
        const void* W1, const void* W2, const void* W3) {
    const int wsel = id % 3;
    const void* Wm = (wsel == 0 ? W1 : (wsel == 1 ? W2 : W3));
    const int ofs = (id / 3) * 16384;
    const int tx = tid & 31, ty = tid >> 5;
    float* rowbuf = lds;          // [2][4][128]: rows K..K+3
    float* colbuf = lds + 1024;   // [2][4][128]: cols K..K+3 packed [j][ty*16+m]
    float4f V[16];                // A[ty+8m][4tx..4tx+3]
#pragma unroll
    for (int m = 0; m < 16; ++m) {
        int base = ofs + (ty + 8 * m) * 128 + 4 * tx;
        if (ISF32) {
            V[m] = *(const float4f*)((const float*)Wm + base);
        } else {
            ushort4 u = *(const ushort4*)((const unsigned short*)Wm + base);
            V[m] = (float4f){bf2f(u.x), bf2f(u.y), bf2f(u.z), bf2f(u.w)};
        }
    }
    if (ty < 4) *(float4f*)&rowbuf[ty * 128 + 4 * tx] = V[0];
    if (tx == 0) {
#pragma unroll
        for (int j = 0; j < 4; ++j) {
#pragma unroll
            for (int mg = 0; mg < 4; ++mg) {
                float4f t = {V[mg * 4 + 0][j], V[mg * 4 + 1][j],
                             V[mg * 4 + 2][j], V[mg * 4 + 3][j]};
                *(float4f*)&colbuf[j * 128 + ty * 16 + mg * 4] = t;
            }
        }
    }
    __syncthreads();
    float logacc = 0.0f;
#pragma unroll 1
    for (int kap = 0; kap < 32; ++kap) {
        const int K = kap * 4;
        const int buf = (kap & 1) * 512;
        float4f D[4], R[4], C[4][4];
#pragma unroll
        for (int j = 0; j < 4; ++j) {
            D[j] = *(const float4f*)&rowbuf[buf + j * 128 + K];       // broadcast
            R[j] = *(const float4f*)&rowbuf[buf + j * 128 + 4 * tx];
#pragma unroll
            for (int mg = 0; mg < 4; ++mg)
                C[j][mg] = *(const float4f*)&colbuf[buf + j * 128 + ty * 16 + mg * 4];
        }
        float p0 = D[0][0], i0 = 1.0f / p0;
        float l10 = D[1][0] * i0, l20 = D[2][0] * i0, l30 = D[3][0] * i0;
        D[1] = vmsub(D[1], l10, D[0]); R[1] = vmsub(R[1], l10, R[0]);
        D[2] = vmsub(D[2], l20, D[0]); R[2] = vmsub(R[2], l20, R[0]);
        D[3] = vmsub(D[3], l30, D[0]); R[3] = vmsub(R[3], l30, R[0]);
        float p1 = D[1][1], i1 = 1.0f / p1;
        float l21 = D[2][1] * i1, l31 = D[3][1] * i1;
        D[2] = vmsub(D[2], l21, D[1]); R[2] = vmsub(R[2], l21, R[1]);
        D[3] = vmsub(D[3], l31, D[1]); R[3] = vmsub(R[3], l31, R[1]);
        float p2 = D[2][2], i2 = 1.0f / p2;
        float l32 = D[3][2] * i2;
        D[3] = vmsub(D[3], l32, D[2]); R[3] = vmsub(R[3], l32, R[2]);
        float p3 = D[3][3], i3 = 1.0f / p3;
        logacc += __log2f(fabsf(p0)) + __log2f(fabsf(p1))
                + __log2f(fabsf(p2)) + __log2f(fabsf(p3));
        float4f X3 = vscale(R[3], i3);
        float4f X2 = vscale(vmsub(R[2], D[2][3], X3), i2);
        float4f X1 = vscale(vmsub(vmsub(R[1], D[1][2], X2), D[1][3], X3), i1);
        float4f X0 = vscale(vmsub(vmsub(vmsub(R[0], D[0][1], X1),
                                        D[0][2], X2), D[0][3], X3), i0);
#pragma unroll
        for (int mg = 0; mg < 4; ++mg) {
#pragma unroll
            for (int e = 0; e < 4; ++e) {
                float4f v = V[mg * 4 + e];
                v = vmsub(v, C[0][mg][e], X0);
                v = vmsub(v, C[1][mg][e], X1);
                v = vmsub(v, C[2][mg][e], X2);
                v = vmsub(v, C[3][mg][e], X3);
                V[mg * 4 + e] = v;
            }
        }
        if (kap < 31) {
            const int nbuf = ((kap + 1) & 1) * 512;
            const int tb = (kap & 1) ? 0 : 4;
            const int mn = (kap + 1) >> 1;
            if (ty >= tb && ty < tb + 4) {
                float4f val;
                switch (mn) {
                case 0:  val = V[0];  break; case 1:  val = V[1];  break;
                case 2:  val = V[2];  break; case 3:  val = V[3];  break;
                case 4:  val = V[4];  break; case 5:  val = V[5];  break;
                case 6:  val = V[6];  break; case 7:  val = V[7];  break;
                case 8:  val = V[8];  break; case 9:  val = V[9];  break;
                case 10: val = V[10]; break; case 11: val = V[11]; break;
                case 12: val = V[12]; break; case 13: val = V[13]; break;
                case 14: val = V[14]; break; default: val = V[15]; break;
                }
                *(float4f*)&rowbuf[nbuf + (ty - tb) * 128 + 4 * tx] = val;
            }
            if (tx == kap + 1) {
#pragma unroll
                for (int j = 0; j < 4; ++j) {
#pragma unroll
                    for (int mg = 0; mg < 4; ++mg) {
                        float4f t = {V[mg * 4 + 0][j], V[mg * 4 + 1][j],
                                     V[mg * 4 + 2][j], V[mg * 4 + 3][j]};
                        *(float4f*)&colbuf[nbuf + j * 128 + ty * 16 + mg * 4] = t;
                    }
                }
            }
        }
        __syncthreads();
    }
    return logacc * LN2;
}

__global__ __launch_bounds__(256, 1) void k_main(
        const void* __restrict__ x,
        const void* __restrict__ W1, const void* __restrict__ b1,
        const void* __restrict__ W2, const void* __restrict__ b2,
        const void* __restrict__ W3, const void* __restrict__ b3,
        void* __restrict__ out, float* __restrict__ ws) {
    extern __shared__ __align__(16) char ldsb[];
    __shared__ int s_last;
    const int tid = threadIdx.x;
    const int lane = tid & 63;
    const int isf32 = detect_f32((const unsigned short*)W1, lane);

    if (blockIdx.x < 12) {
        float ld = isf32 ? lu_logdet<1>(blockIdx.x, tid, (float*)ldsb, W1, W2, W3)
                         : lu_logdet<0>(blockIdx.x, tid, (float*)ldsb, W1, W2, W3);
        if (tid == 0) ws[2 + blockIdx.x] = ld;
    } else {
        const int bid = blockIdx.x - 12;
        if (isf32) fwd<1>(bid, tid, lane, ldsb, x, ws, out, ws);
        else       fwd<0>(bid, tid, lane, ldsb, x, ws, out, ws);
    }

    // ---- last-block finalize ----
    __threadfence();
    if (tid == 0) s_last = (atomicAdd((int*)ws, 1) == NBLK - 1);
    __syncthreads();
    if (!s_last) return;
    __threadfence();   // acquire: other blocks' ws writes now visible
    float s = 0.0f;
#pragma unroll
    for (int i = 0; i < 12; ++i) s += ws[2 + i];
    for (int b = tid; b < 4096; b += 256) {
        float v = s + LOG_SLOPE * ws[64 + b];
        if (isf32) ((float*)out)[524288 + b] = v;
        else ((unsigned short*)out)[524288 + b] = f2bf(v);
    }
}

extern "C" void kernel_launch(void* const* d_in, const int* in_sizes, int n_in,
                              void* d_out, int out_size, void* d_ws, size_t ws_size,
                              hipStream_t stream) {
    const void* x  = d_in[0];
    const void* W1 = d_in[1];
    const void* b1 = d_in[2];
    const void* W2 = d_in[3];
    const void* b2 = d_in[4];
    const void* W3 = d_in[5];
    const void* b3 = d_in[6];
    float* ws = (float*)d_ws;

    hipLaunchKernelGGL(k_prep, dim3(97), dim3(256), 0, stream,
                       W1, W2, W3, b1, b2, b3, ws);
    hipLaunchKernelGGL(k_main, dim3(NBLK), dim3(256), LDS_BYTES, stream,
                       x, W1, b1, W2, b2, W3, b3, d_out, ws);
}

// Round 12
// 119.146 us; speedup vs baseline: 2.9966x; 1.0332x over previous
//
#include <hip/hip_runtime.h>

typedef __attribute__((ext_vector_type(8))) short short8;
typedef __attribute__((ext_vector_type(4))) float float4f;
typedef __attribute__((ext_vector_type(4))) unsigned short us4;

#define PITCH 136   // shorts/row in LDS planes
#define ROWS 32     // rows per fwd block
#define LOG_SLOPE -2.302585092994046f   // log(0.1)
#define LN2 0.6931471805599453f
#define NBLK 140    // 12 LU + 128 fwd
#define LDS_BYTES 69760   // 8 planes * 32*136*2 + 128 cnt
// ws layout (floats): [0] ticket | [2..13] logdet partials | [64..4159] counts
// [4160..5695] fp32 biases | [8192..] W hi/lo ushort planes (TILED layout, r11)
#define WS_BIAS 4160
#define WS_WPLANES 8192
#define NWELEM 196608   // 12 * 16384

__device__ __forceinline__ float bf2f(unsigned int u) {
    return __builtin_bit_cast(float, u << 16);
}
__device__ __forceinline__ unsigned short f2bf(float f) {
    unsigned int x = __builtin_bit_cast(unsigned int, f);
    x += 0x7fff + ((x >> 16) & 1);   // round-to-nearest-even
    return (unsigned short)(x >> 16);
}
__device__ __forceinline__ float4f vmsub(float4f a, float s, float4f b) {
    a[0] -= s * b[0]; a[1] -= s * b[1]; a[2] -= s * b[2]; a[3] -= s * b[3];
    return a;
}
__device__ __forceinline__ float4f vscale(float4f a, float s) {
    a[0] *= s; a[1] *= s; a[2] *= s; a[3] *= s;
    return a;
}

// Barrier with LDS-only drain (r10): orders ds_write/ds_read across waves but
// does NOT force vmcnt(0) — weight prefetch loads stay in flight across the
// barrier; compiler inserts counted vmcnt before first use.
__device__ __forceinline__ void bar_lgkm() {
    asm volatile("s_waitcnt lgkmcnt(0)\n\ts_barrier" ::: "memory");
}

template<int ISF32>
__device__ __forceinline__ float ldv(const void* p, int i) {
    if (ISF32) return ((const float*)p)[i];
    return bf2f(((const unsigned short*)p)[i]);
}

// Per-wave dtype sniff: fp32 weights read as u16 pairs have uniform-random
// mantissa halves; bf16 weights have exponent fields in a narrow band.
__device__ __forceinline__ int detect_f32(const unsigned short* W1u, int lane) {
    unsigned int u = W1u[lane * 2];
    unsigned int e = (u >> 7) & 0xFF;
    int bad = (e < 64) || (e > 135);
    return __ballot(bad) != 0ull;
}

__device__ __forceinline__ float4f mfma16(short8 a, short8 b, float4f c) {
    return __builtin_amdgcn_mfma_f32_16x16x32_bf16(a, b, c, 0, 0, 0);
}

__device__ __forceinline__ void split8(float4f a, float4f b, short8& hi, short8& lo) {
#pragma unroll
    for (int j = 0; j < 4; ++j) {
        float v = a[j]; unsigned short h = f2bf(v);
        hi[j] = (short)h; lo[j] = (short)f2bf(v - bf2f(h));
        v = b[j]; h = f2bf(v);
        hi[4 + j] = (short)h; lo[4 + j] = (short)f2bf(v - bf2f(h));
    }
}

// ---- prep: W -> bf16 hi/lo planes (TILED: one wave's loadW instruction reads
// one contiguous 1KB block, r11), biases -> fp32, zero ticket.
__global__ void k_prep(const void* __restrict__ W1, const void* __restrict__ W2,
                       const void* __restrict__ W3, const void* __restrict__ b1,
                       const void* __restrict__ b2, const void* __restrict__ b3,
                       float* __restrict__ ws) {
    const int tid = threadIdx.x, bid = blockIdx.x;
    const int isf32 = detect_f32((const unsigned short*)W1, tid & 63);
    unsigned short* whi = (unsigned short*)(ws + WS_WPLANES);
    unsigned short* wlo = whi + NWELEM;
    if (bid < 96) {
        int s = (bid * 256 + tid) * 8;        // 96*256*8 = 196608
        int mat = s >> 14, off = s & 16383;   // mat = wsel*4 + layer
        int wsel = mat >> 2;
        const void* Wm = wsel == 0 ? W1 : (wsel == 1 ? W2 : W3);
        int src = (mat & 3) * 16384 + off;
        short8 hi, lo;
        if (isf32) {
            const float* p = (const float*)Wm + src;
            split8(*(const float4f*)p, *(const float4f*)(p + 4), hi, lo);
        } else {
            hi = *(const short8*)((const unsigned short*)Wm + src);
            lo = (short8){0, 0, 0, 0, 0, 0, 0, 0};
        }
        // tiled destination offset (8-short chunk: fixed c, k..k+7)
        int c = off >> 7, k = off & 127;
        int kk = k >> 5, q = (k >> 3) & 3;
        int cb = c >> 4, m = c & 15;
        int noff = kk * 4096 + cb * 512 + m * 32 + q * 8;
        *(short8*)(whi + mat * 16384 + noff) = hi;
        *(short8*)(wlo + mat * 16384 + noff) = lo;
    } else {
        for (int e = tid; e < 1536; e += 256) {
            int bsel = e >> 9, idx = e & 511;
            const void* bp = bsel == 0 ? b1 : (bsel == 1 ? b2 : b3);
            ws[WS_BIAS + e] = isf32 ? ((const float*)bp)[idx]
                                    : bf2f(((const unsigned short*)bp)[idx]);
        }
        if (tid == 0) ((int*)ws)[0] = 0;   // finalize ticket
    }
}

// Weight fragment set for one matvec: [kk]{w0h,w1h,w0l,w1l}. All static indices.
struct W8 { short8 v[16]; };

// Tiled-layout load: per instruction, 64 lanes cover one contiguous 1KB block.
__device__ __forceinline__ W8 loadW(const unsigned short* __restrict__ wh,
                                    const unsigned short* __restrict__ wl,
                                    int cb, int mq) {
    W8 r;
#pragma unroll
    for (int kk = 0; kk < 4; ++kk) {
        const int o0 = kk * 4096 + cb * 512 + mq;
        const int o1 = o0 + 512;
        r.v[kk * 4 + 0] = *(const short8*)(wh + o0);
        r.v[kk * 4 + 1] = *(const short8*)(wh + o1);
        r.v[kk * 4 + 2] = *(const short8*)(wl + o0);
        r.v[kk * 4 + 3] = *(const short8*)(wl + o1);
    }
    return r;
}

// out[ROWS x 128] = act( in[ROWS x 128] @ W^T + bias ); ping-pong planes,
// one lgkm-barrier per matvec. r12: SWAPPED-OPERAND MFMA — mfma16(w, x)
// computes the transposed fragment D[wcol][xrow]: lane holds xrow = m fixed
// and 4 CONTIGUOUS wcols (colb + ct*16 + q*4 + 0..3). Same dot-products, same
// accumulation order -> bit-identical values, transposed lane placement.
// Epilogue becomes vector: 8 ds_write_b64 instead of 32 ds_write_b16; res
// reads 8 b64 instead of 32 b16; bias = 4 aligned float4 loads.
// MODE 0: out = leaky(v) | 1: out = res + v | 2: out = leaky(v)+count | 3: count only
template<int MODE, int DOLOAD>
__device__ __forceinline__ W8 matvec(const W8& w,
        const unsigned short* inh, const unsigned short* inl,
        unsigned short* outh, unsigned short* outl,
        const unsigned short* resh, const unsigned short* resl,
        const unsigned short* __restrict__ nwh, const unsigned short* __restrict__ nwl,
        const float* __restrict__ bias,
        int lane, int colb, int* cnt) {
    const int m = lane & 15, q = lane >> 4;
    float4f b0 = *(const float4f*)(bias + colb + q * 4);
    float4f b1 = *(const float4f*)(bias + colb + 16 + q * 4);
    float4f acc[2][2];
    acc[0][0] = b0; acc[0][1] = b1;
    acc[1][0] = b0; acc[1][1] = b1;
    bar_lgkm();   // previous matvec's LDS writes visible; vmcnt NOT drained
    W8 wn;
    if constexpr (DOLOAD) {
        wn = loadW(nwh, nwl, colb >> 4, m * 32 + q * 8);   // coalesced prefetch
    }
#pragma unroll
    for (int kk = 0; kk < 4; ++kk) {
        const int kc = kk * 32 + q * 8;
#pragma unroll
        for (int rt = 0; rt < 2; ++rt) {
            short8 xh = *(const short8*)(inh + (rt * 16 + m) * PITCH + kc);
            short8 xl = *(const short8*)(inl + (rt * 16 + m) * PITCH + kc);
            acc[rt][0] = mfma16(w.v[kk * 4 + 0], xh, acc[rt][0]);
            acc[rt][0] = mfma16(w.v[kk * 4 + 0], xl, acc[rt][0]);
            acc[rt][0] = mfma16(w.v[kk * 4 + 2], xh, acc[rt][0]);
            acc[rt][1] = mfma16(w.v[kk * 4 + 1], xh, acc[rt][1]);
            acc[rt][1] = mfma16(w.v[kk * 4 + 1], xl, acc[rt][1]);
            acc[rt][1] = mfma16(w.v[kk * 4 + 3], xh, acc[rt][1]);
        }
    }
    int cc[2] = {0, 0};
#pragma unroll
    for (int rt = 0; rt < 2; ++rt) {
#pragma unroll
        for (int ct = 0; ct < 2; ++ct) {
            float4f v = acc[rt][ct];
            const int o = (rt * 16 + m) * PITCH + colb + ct * 16 + q * 4;
            if (MODE == 1) {
                us4 rh = *(const us4*)(resh + o);
                us4 rl = *(const us4*)(resl + o);
#pragma unroll
                for (int j = 0; j < 4; ++j) v[j] += bf2f(rh[j]) + bf2f(rl[j]);
            }
            if (MODE >= 2) {
#pragma unroll
                for (int j = 0; j < 4; ++j) cc[rt] += (v[j] <= 0.0f) ? 1 : 0;
            }
            if (MODE == 0 || MODE == 2) {
#pragma unroll
                for (int j = 0; j < 4; ++j) v[j] = v[j] > 0.0f ? v[j] : 0.1f * v[j];
            }
            if (MODE != 3) {
                us4 h, l;
#pragma unroll
                for (int j = 0; j < 4; ++j) {
                    unsigned short hh = f2bf(v[j]);
                    h[j] = hh;
                    l[j] = f2bf(v[j] - bf2f(hh));
                }
                *(us4*)(outh + o) = h;
                *(us4*)(outl + o) = l;
            }
        }
    }
    if (MODE >= 2) {
        // per-row count: lanes m, m+16, m+32, m+48 hold the 4 q-slices of
        // the wave's 32 cols for row rt*16+m -> reduce across q (xor 16,32)
#pragma unroll
        for (int rt = 0; rt < 2; ++rt) {
            int c = cc[rt];
            c += __shfl_xor(c, 16);
            c += __shfl_xor(c, 32);
            if (q == 0) atomicAdd(&cnt[rt * 16 + m], c);
        }
    }
    if constexpr (DOLOAD) return wn;
    else return w;   // unused by callers; keeps a defined value
}

// Per-layer weight-set ledger (each W8 = 64 VGPR, max 3 live = 192):
//   h1 uses A=w1[L], loads B=w2[L] | h2 uses B, loads C=w3[L] | res uses C
//   g1 uses A (HELD) | g2 uses B (HELD), loads A=w1[L+1]
// 3 loads/layer instead of 5 -> per-block weight traffic 1.28MB -> 0.77MB.
template<int ISF32>
__device__ __forceinline__ void fwd(int bid, int tid, int lane, char* ldsb,
                                    const void* x, const float* ws, void* out,
                                    float* wsw) {
    unsigned short* P = (unsigned short*)ldsb;
    unsigned short* Ah = P;
    unsigned short* Al = P + 1 * ROWS * PITCH;
    unsigned short* Bh = P + 2 * ROWS * PITCH;
    unsigned short* Bl = P + 3 * ROWS * PITCH;
    unsigned short* Th = P + 4 * ROWS * PITCH;
    unsigned short* Tl = P + 5 * ROWS * PITCH;
    unsigned short* Uh = P + 6 * ROWS * PITCH;
    unsigned short* Ul = P + 7 * ROWS * PITCH;
    int* cnt = (int*)(P + 8 * ROWS * PITCH);
    const unsigned short* whi = (const unsigned short*)(ws + WS_WPLANES);
    const unsigned short* wlo = whi + NWELEM;
    const float* bias = ws + WS_BIAS;
    const int r0 = bid * ROWS;
    const int m = lane & 15, q = lane >> 4;
    const int colb = (tid >> 6) * 32;
    // prefetch layer-0 w1 while staging x into LDS
    W8 wA = loadW(whi, wlo, colb >> 4, m * 32 + q * 8);
    W8 wB, wC;
    for (int e = tid; e < ROWS * 128; e += 256) {
        int r = e >> 7, c = e & 127;
        float v = ldv<ISF32>(x, (r0 + r) * 128 + c);
        unsigned short h = f2bf(v);
        Ah[r * PITCH + c] = h;
        Al[r * PITCH + c] = f2bf(v - bf2f(h));
    }
    if (tid < ROWS) cnt[tid] = 0;
    unsigned short *curh = Ah, *curl = Al, *othh = Bh, *othl = Bl;
#pragma unroll 1
    for (int layer = 0; layer < 4; ++layer) {
        const unsigned short* w2h = whi + (4 + layer) * 16384;
        const unsigned short* w2l = wlo + (4 + layer) * 16384;
        const unsigned short* w3h = whi + (8 + layer) * 16384;
        const unsigned short* w3l = wlo + (8 + layer) * 16384;
        const unsigned short* n1h = whi + ((layer + 1) & 3) * 16384;  // next-layer w1
        const unsigned short* n1l = wlo + ((layer + 1) & 3) * 16384;
        const float* b1p = bias + layer * 128;
        const float* b2p = bias + 512 + layer * 128;
        const float* b3p = bias + 1024 + layer * 128;
        wB = matvec<0, 1>(wA, curh, curl, Th, Tl, 0, 0, w2h, w2l, b1p, lane, colb, cnt);
        wC = matvec<0, 1>(wB, Th, Tl, Uh, Ul, 0, 0, w3h, w3l, b2p, lane, colb, cnt);
        matvec<1, 0>(wC, Uh, Ul, othh, othl, curh, curl, 0, 0, b3p, lane, colb, cnt);
        matvec<2, 0>(wA, othh, othl, Th, Tl, 0, 0, 0, 0, b1p, lane, colb, cnt);
        wA = matvec<3, 1>(wB, Th, Tl, Th, Tl, 0, 0, n1h, n1l, b2p, lane, colb, cnt);
        unsigned short* t;
        t = curh; curh = othh; othh = t;
        t = curl; curl = othl; othl = t;
    }
    bar_lgkm();
    for (int e = tid; e < ROWS * 128; e += 256) {
        int r = e >> 7, c = e & 127;
        float v = bf2f(curh[r * PITCH + c]) + bf2f(curl[r * PITCH + c]);
        if (ISF32) ((float*)out)[(r0 + r) * 128 + c] = v;
        else ((unsigned short*)out)[(r0 + r) * 128 + c] = f2bf(v);
    }
    if (tid < ROWS) wsw[64 + r0 + tid] = (float)cnt[tid];
}

// ---- register-resident unpivoted LU, RANK-4 per barrier (32 intervals).
// Trailing update via V -= C_raw * (Upanel^{-1} R) (r6 identity). Reads raw W.
template<int ISF32>
__device__ __forceinline__ float lu_logdet(int id, int tid, float* lds,
        const void* W1, const void* W2, const void* W3) {
    const int wsel = id % 3;
    const void* Wm = (wsel == 0 ? W1 : (wsel == 1 ? W2 : W3));
    const int ofs = (id / 3) * 16384;
    const int tx = tid & 31, ty = tid >> 5;
    float* rowbuf = lds;          // [2][4][128]: rows K..K+3
    float* colbuf = lds + 1024;   // [2][4][128]: cols K..K+3 packed [j][ty*16+m]
    float4f V[16];                // A[ty+8m][4tx..4tx+3]
#pragma unroll
    for (int m = 0; m < 16; ++m) {
        int base = ofs + (ty + 8 * m) * 128 + 4 * tx;
        if (ISF32) {
            V[m] = *(const float4f*)((const float*)Wm + base);
        } else {
            ushort4 u = *(const ushort4*)((const unsigned short*)Wm + base);
            V[m] = (float4f){bf2f(u.x), bf2f(u.y), bf2f(u.z), bf2f(u.w)};
        }
    }
    if (ty < 4) *(float4f*)&rowbuf[ty * 128 + 4 * tx] = V[0];
    if (tx == 0) {
#pragma unroll
        for (int j = 0; j < 4; ++j) {
#pragma unroll
            for (int mg = 0; mg < 4; ++mg) {
                float4f t = {V[mg * 4 + 0][j], V[mg * 4 + 1][j],
                             V[mg * 4 + 2][j], V[mg * 4 + 3][j]};
                *(float4f*)&colbuf[j * 128 + ty * 16 + mg * 4] = t;
            }
        }
    }
    __syncthreads();
    float logacc = 0.0f;
#pragma unroll 1
    for (int kap = 0; kap < 32; ++kap) {
        const int K = kap * 4;
        const int buf = (kap & 1) * 512;
        float4f D[4], R[4], C[4][4];
#pragma unroll
        for (int j = 0; j < 4; ++j) {
            D[j] = *(const float4f*)&rowbuf[buf + j * 128 + K];       // broadcast
            R[j] = *(const float4f*)&rowbuf[buf + j * 128 + 4 * tx];
#pragma unroll
            for (int mg = 0; mg < 4; ++mg)
                C[j][mg] = *(const float4f*)&colbuf[buf + j * 128 + ty * 16 + mg * 4];
        }
        float p0 = D[0][0], i0 = 1.0f / p0;
        float l10 = D[1][0] * i0, l20 = D[2][0] * i0, l30 = D[3][0] * i0;
        D[1] = vmsub(D[1], l10, D[0]); R[1] = vmsub(R[1], l10, R[0]);
        D[2] = vmsub(D[2], l20, D[0]); R[2] = vmsub(R[2], l20, R[0]);
        D[3] = vmsub(D[3], l30, D[0]); R[3] = vmsub(R[3], l30, R[0]);
        float p1 = D[1][1], i1 = 1.0f / p1;
        float l21 = D[2][1] * i1, l31 = D[3][1] * i1;
        D[2] = vmsub(D[2], l21, D[1]); R[2] = vmsub(R[2], l21, R[1]);
        D[3] = vmsub(D[3], l31, D[1]); R[3] = vmsub(R[3], l31, R[1]);
        float p2 = D[2][2], i2 = 1.0f / p2;
        float l32 = D[3][2] * i2;
        D[3] = vmsub(D[3], l32, D[2]); R[3] = vmsub(R[3], l32, R[2]);
        float p3 = D[3][3], i3 = 1.0f / p3;
        logacc += __log2f(fabsf(p0)) + __log2f(fabsf(p1))
                + __log2f(fabsf(p2)) + __log2f(fabsf(p3));
        float4f X3 = vscale(R[3], i3);
        float4f X2 = vscale(vmsub(R[2], D[2][3], X3), i2);
        float4f X1 = vscale(vmsub(vmsub(R[1], D[1][2], X2), D[1][3], X3), i1);
        float4f X0 = vscale(vmsub(vmsub(vmsub(R[0], D[0][1], X1),
                                        D[0][2], X2), D[0][3], X3), i0);
#pragma unroll
        for (int mg = 0; mg < 4; ++mg) {
#pragma unroll
            for (int e = 0; e < 4; ++e) {
                float4f v = V[mg * 4 + e];
                v = vmsub(v, C[0][mg][e], X0);
                v = vmsub(v, C[1][mg][e], X1);
                v = vmsub(v, C[2][mg][e], X2);
                v = vmsub(v, C[3][mg][e], X3);
                V[mg * 4 + e] = v;
            }
        }
        if (kap < 31) {
            const int nbuf = ((kap + 1) & 1) * 512;
            const int tb = (kap & 1) ? 0 : 4;
            const int mn = (kap + 1) >> 1;
            if (ty >= tb && ty < tb + 4) {
                float4f val;
                switch (mn) {
                case 0:  val = V[0];  break; case 1:  val = V[1];  break;
                case 2:  val = V[2];  break; case 3:  val = V[3];  break;
                case 4:  val = V[4];  break; case 5:  val = V[5];  break;
                case 6:  val = V[6];  break; case 7:  val = V[7];  break;
                case 8:  val = V[8];  break; case 9:  val = V[9];  break;
                case 10: val = V[10]; break; case 11: val = V[11]; break;
                case 12: val = V[12]; break; case 13: val = V[13]; break;
                case 14: val = V[14]; break; default: val = V[15]; break;
                }
                *(float4f*)&rowbuf[nbuf + (ty - tb) * 128 + 4 * tx] = val;
            }
            if (tx == kap + 1) {
#pragma unroll
                for (int j = 0; j < 4; ++j) {
#pragma unroll
                    for (int mg = 0; mg < 4; ++mg) {
                        float4f t = {V[mg * 4 + 0][j], V[mg * 4 + 1][j],
                                     V[mg * 4 + 2][j], V[mg * 4 + 3][j]};
                        *(float4f*)&colbuf[nbuf + j * 128 + ty * 16 + mg * 4] = t;
                    }
                }
            }
        }
        __syncthreads();
    }
    return logacc * LN2;
}

__global__ __launch_bounds__(256, 1) void k_main(
        const void* __restrict__ x,
        const void* __restrict__ W1, const void* __restrict__ b1,
        const void* __restrict__ W2, const void* __restrict__ b2,
        const void* __restrict__ W3, const void* __restrict__ b3,
        void* __restrict__ out, float* __restrict__ ws) {
    extern __shared__ __align__(16) char ldsb[];
    __shared__ int s_last;
    const int tid = threadIdx.x;
    const int lane = tid & 63;
    const int isf32 = detect_f32((const unsigned short*)W1, lane);

    if (blockIdx.x < 12) {
        float ld = isf32 ? lu_logdet<1>(blockIdx.x, tid, (float*)ldsb, W1, W2, W3)
                         : lu_logdet<0>(blockIdx.x, tid, (float*)ldsb, W1, W2, W3);
        if (tid == 0) ws[2 + blockIdx.x] = ld;
    } else {
        const int bid = blockIdx.x - 12;
        if (isf32) fwd<1>(bid, tid, lane, ldsb, x, ws, out, ws);
        else       fwd<0>(bid, tid, lane, ldsb, x, ws, out, ws);
    }

    // ---- last-block finalize ----
    __threadfence();
    if (tid == 0) s_last = (atomicAdd((int*)ws, 1) == NBLK - 1);
    __syncthreads();
    if (!s_last) return;
    __threadfence();   // acquire: other blocks' ws writes now visible
    float s = 0.0f;
#pragma unroll
    for (int i = 0; i < 12; ++i) s += ws[2 + i];
    for (int b = tid; b < 4096; b += 256) {
        float v = s + LOG_SLOPE * ws[64 + b];
        if (isf32) ((float*)out)[524288 + b] = v;
        else ((unsigned short*)out)[524288 + b] = f2bf(v);
    }
}

extern "C" void kernel_launch(void* const* d_in, const int* in_sizes, int n_in,
                              void* d_out, int out_size, void* d_ws, size_t ws_size,
                              hipStream_t stream) {
    const void* x  = d_in[0];
    const void* W1 = d_in[1];
    const void* b1 = d_in[2];
    const void* W2 = d_in[3];
    const void* b2 = d_in[4];
    const void* W3 = d_in[5];
    const void* b3 = d_in[6];
    float* ws = (float*)d_ws;

    hipLaunchKernelGGL(k_prep, dim3(97), dim3(256), 0, stream,
                       W1, W2, W3, b1, b2, b3, ws);
    hipLaunchKernelGGL(k_main, dim3(NBLK), dim3(256), LDS_BYTES, stream,
                       x, W1, b1, W2, b2, W3, b3, d_out, ws);
}